// Round 1
// baseline (937.329 us; speedup 1.0000x reference)
//
#include <hip/hip_runtime.h>
#include <hip/hip_bf16.h>
#include <math.h>

#define B_DIM 4
#define S_DIM 1024
#define D_DIM 1024
#define H_DIM 16
#define HD_DIM 64

// ---------------------------------------------------------------------------
// GEMM: Out = X @ W + bias   (M=4096, N=K=1024, all fp32, row-major)
// 128x128 tile, BK=8, 256 threads, 8x8 micro-tile per thread.
// ---------------------------------------------------------------------------
#define BM 128
#define BN 128
#define BK 8
#define LDP 132  // padded LDS row (floats), 16B-aligned, breaks pow2 strides

__global__ __launch_bounds__(256) void gemm_bias_kernel(
    const float* __restrict__ X, const float* __restrict__ W,
    const float* __restrict__ bias, float* __restrict__ Out)
{
    __shared__ float As[BK][LDP];  // transposed: As[k][m]
    __shared__ float Bs[BK][LDP];  // natural:    Bs[k][n]

    const int tid = threadIdx.x;
    const int m0 = blockIdx.y * BM;
    const int n0 = blockIdx.x * BN;
    const int ty = tid >> 4;   // 0..15
    const int tx = tid & 15;   // 0..15

    // global load mapping
    const int ar = tid >> 1;           // 0..127  (A row in tile)
    const int ac = (tid & 1) << 2;     // 0 or 4  (A k-offset)
    const int br = tid >> 5;           // 0..7    (B k-row in tile)
    const int bc = (tid & 31) << 2;    // 0..124  (B col)

    float acc[8][8];
#pragma unroll
    for (int i = 0; i < 8; ++i)
#pragma unroll
        for (int j = 0; j < 8; ++j) acc[i][j] = 0.f;

    const float* Aptr = X + (long)(m0 + ar) * D_DIM + ac;
    const float* Bptr = W + (long)br * D_DIM + n0 + bc;

    for (int k0 = 0; k0 < D_DIM; k0 += BK) {
        float4 av = *(const float4*)(Aptr + k0);
        float4 bv = *(const float4*)(Bptr + (long)k0 * D_DIM);
        __syncthreads();
        As[ac + 0][ar] = av.x;
        As[ac + 1][ar] = av.y;
        As[ac + 2][ar] = av.z;
        As[ac + 3][ar] = av.w;
        *(float4*)&Bs[br][bc] = bv;
        __syncthreads();
#pragma unroll
        for (int kk = 0; kk < BK; ++kk) {
            float4 a0 = *(const float4*)&As[kk][ty * 4];
            float4 a1 = *(const float4*)&As[kk][64 + ty * 4];
            float4 b0 = *(const float4*)&Bs[kk][tx * 4];
            float4 b1 = *(const float4*)&Bs[kk][64 + tx * 4];
            float a[8] = {a0.x, a0.y, a0.z, a0.w, a1.x, a1.y, a1.z, a1.w};
            float b[8] = {b0.x, b0.y, b0.z, b0.w, b1.x, b1.y, b1.z, b1.w};
#pragma unroll
            for (int i = 0; i < 8; ++i)
#pragma unroll
                for (int j = 0; j < 8; ++j)
                    acc[i][j] = fmaf(a[i], b[j], acc[i][j]);
        }
    }

#pragma unroll
    for (int i = 0; i < 8; ++i) {
        int row = m0 + ((i < 4) ? (ty * 4 + i) : (64 + ty * 4 + (i - 4)));
#pragma unroll
        for (int jh = 0; jh < 2; ++jh) {
            int col = n0 + jh * 64 + tx * 4;
            float4 o;
            o.x = acc[i][jh * 4 + 0] + bias[col + 0];
            o.y = acc[i][jh * 4 + 1] + bias[col + 1];
            o.z = acc[i][jh * 4 + 2] + bias[col + 2];
            o.w = acc[i][jh * 4 + 3] + bias[col + 3];
            *(float4*)&Out[(long)row * D_DIM + col] = o;
        }
    }
}

// ---------------------------------------------------------------------------
// RoPE (in-place), interleaved-input -> split-output variant:
//   out[i]    = x[2i]*cos - x[2i+1]*sin     (i < 32)
//   out[i+32] = x[2i]*sin + x[2i+1]*cos
// One block per row (b*S+s); precise sincosf/powf (angle up to ~1023 rad).
// ---------------------------------------------------------------------------
__global__ __launch_bounds__(256) void rope_kernel(float* Q, float* K)
{
    const int row = blockIdx.x;            // 0..B*S-1
    const int pos = row & (S_DIM - 1);
    float* buf = ((blockIdx.y == 0) ? Q : K) + (long)row * D_DIM;
    const int tid = threadIdx.x;

    float o1[2], o2[2];
    int i1[2], i2[2];
#pragma unroll
    for (int it = 0; it < 2; ++it) {
        int p = tid + it * 256;            // pair id 0..511
        int h = p >> 5;
        int i = p & 31;
        float x1 = buf[h * 64 + 2 * i];
        float x2 = buf[h * 64 + 2 * i + 1];
        float inv = powf(10000.0f, -(float)(2 * i) / 64.0f);
        float ang = (float)pos * inv;
        float s, c;
        sincosf(ang, &s, &c);
        o1[it] = x1 * c - x2 * s;
        o2[it] = x1 * s + x2 * c;
        i1[it] = h * 64 + i;
        i2[it] = h * 64 + i + 32;
    }
    __syncthreads();
#pragma unroll
    for (int it = 0; it < 2; ++it) {
        buf[i1[it]] = o1[it];
        buf[i2[it]] = o2[it];
    }
}

// ---------------------------------------------------------------------------
// Flash-style causal attention, fp32.
// Block = 256 threads, handles one (b, h, 64-row q tile).
// Score & PV phases are 64x64x64 outer-product GEMMs through LDS.
// ---------------------------------------------------------------------------
#define APAD 68

__global__ __launch_bounds__(256) void attn_kernel(
    const float* __restrict__ Q, const float* __restrict__ K,
    const float* __restrict__ V, float* __restrict__ CTX)
{
    __shared__ float Qt[HD_DIM][APAD];  // [d][q]   (Q tile transposed)
    __shared__ float Kt[HD_DIM][APAD];  // [d][k]   (K tile transposed)
    __shared__ float Vs[64][APAD];      // [k][d]
    __shared__ float Pt[64][APAD];      // [k][q]   scores -> probs
    __shared__ float alphaS[64];
    __shared__ float lS[64];

    const int tid = threadIdx.x;
    const int qt = blockIdx.x;
    const int h  = blockIdx.y;
    const int b  = blockIdx.z;

    const int ty = tid >> 4, tx = tid & 15;  // tile mapping
    const int qr = tid >> 2, ks = tid & 3;   // softmax mapping (row, slice)

    const long head_off = (long)h * HD_DIM;
    const long q_base = ((long)(b * S_DIM + qt * 64)) * D_DIM + head_off;

    // load Q tile transposed
#pragma unroll
    for (int it = 0; it < 4; ++it) {
        int r = ty + 16 * it;
        float4 v = *(const float4*)&Q[q_base + (long)r * D_DIM + tx * 4];
        Qt[tx * 4 + 0][r] = v.x;
        Qt[tx * 4 + 1][r] = v.y;
        Qt[tx * 4 + 2][r] = v.z;
        Qt[tx * 4 + 3][r] = v.w;
    }

    float m_run = -1e30f, l_run = 0.f;
    float acc[4][4];
#pragma unroll
    for (int i = 0; i < 4; ++i)
#pragma unroll
        for (int j = 0; j < 4; ++j) acc[i][j] = 0.f;

    for (int kt = 0; kt <= qt; ++kt) {
        const long k_base = ((long)(b * S_DIM + kt * 64)) * D_DIM + head_off;
        __syncthreads();  // protect Kt/Vs/Pt from previous-iter readers (also covers Qt)
#pragma unroll
        for (int it = 0; it < 4; ++it) {
            int r = ty + 16 * it;
            float4 kv = *(const float4*)&K[k_base + (long)r * D_DIM + tx * 4];
            Kt[tx * 4 + 0][r] = kv.x;
            Kt[tx * 4 + 1][r] = kv.y;
            Kt[tx * 4 + 2][r] = kv.z;
            Kt[tx * 4 + 3][r] = kv.w;
            float4 vv = *(const float4*)&V[k_base + (long)r * D_DIM + tx * 4];
            *(float4*)&Vs[r][tx * 4] = vv;
        }
        __syncthreads();

        // scores S[q][k], q = ty*4+i, k = tx*4+j
        float sc[4][4];
#pragma unroll
        for (int i = 0; i < 4; ++i)
#pragma unroll
            for (int j = 0; j < 4; ++j) sc[i][j] = 0.f;
#pragma unroll 4
        for (int dd = 0; dd < HD_DIM; ++dd) {
            float4 qa = *(const float4*)&Qt[dd][ty * 4];
            float4 ka = *(const float4*)&Kt[dd][tx * 4];
            float aa[4] = {qa.x, qa.y, qa.z, qa.w};
            float bb[4] = {ka.x, ka.y, ka.z, ka.w};
#pragma unroll
            for (int i = 0; i < 4; ++i)
#pragma unroll
                for (int j = 0; j < 4; ++j)
                    sc[i][j] = fmaf(aa[i], bb[j], sc[i][j]);
        }
        const bool diag = (kt == qt);
#pragma unroll
        for (int i = 0; i < 4; ++i) {
            int ql = ty * 4 + i;
#pragma unroll
            for (int j = 0; j < 4; ++j) {
                int kl = tx * 4 + j;
                float v = sc[i][j] * 0.125f;  // 1/sqrt(64)
                if (diag && kl > ql) v = -1e30f;
                Pt[kl][ql] = v;  // transposed store: [k][q]
            }
        }
        __syncthreads();

        // online softmax: thread owns row qr, k-slice ks (16 scores)
        float pv[16];
#pragma unroll
        for (int j = 0; j < 16; ++j) pv[j] = Pt[ks * 16 + j][qr];
        float mp = -1e30f;
#pragma unroll
        for (int j = 0; j < 16; ++j) mp = fmaxf(mp, pv[j]);
        mp = fmaxf(mp, __shfl_xor(mp, 1));
        mp = fmaxf(mp, __shfl_xor(mp, 2));
        float mnew = fmaxf(m_run, mp);
        float alpha = __expf(m_run - mnew);
        float lp = 0.f;
#pragma unroll
        for (int j = 0; j < 16; ++j) {
            float p = __expf(pv[j] - mnew);
            Pt[ks * 16 + j][qr] = p;
            lp += p;
        }
        lp += __shfl_xor(lp, 1);
        lp += __shfl_xor(lp, 2);
        l_run = l_run * alpha + lp;
        m_run = mnew;
        if (ks == 0) alphaS[qr] = alpha;
        __syncthreads();

        // PV: ctx[q][d] += P[q][k] * V[k][d]; thread (ty->q, tx->d)
#pragma unroll
        for (int i = 0; i < 4; ++i) {
            float al = alphaS[ty * 4 + i];
#pragma unroll
            for (int j = 0; j < 4; ++j) acc[i][j] *= al;
        }
#pragma unroll 4
        for (int k = 0; k < 64; ++k) {
            float4 pa = *(const float4*)&Pt[k][ty * 4];
            float4 vb = *(const float4*)&Vs[k][tx * 4];
            float aa[4] = {pa.x, pa.y, pa.z, pa.w};
            float bb[4] = {vb.x, vb.y, vb.z, vb.w};
#pragma unroll
            for (int i = 0; i < 4; ++i)
#pragma unroll
                for (int j = 0; j < 4; ++j)
                    acc[i][j] = fmaf(aa[i], bb[j], acc[i][j]);
        }
    }

    if (ks == 0) lS[qr] = l_run;
    __syncthreads();

#pragma unroll
    for (int i = 0; i < 4; ++i) {
        int ql = ty * 4 + i;
        float inv_l = 1.0f / lS[ql];
        float4 o;
        o.x = acc[i][0] * inv_l;
        o.y = acc[i][1] * inv_l;
        o.z = acc[i][2] * inv_l;
        o.w = acc[i][3] * inv_l;
        *(float4*)&CTX[q_base + (long)ql * D_DIM + tx * 4] = o;
    }
}

// ---------------------------------------------------------------------------
extern "C" void kernel_launch(void* const* d_in, const int* in_sizes, int n_in,
                              void* d_out, int out_size, void* d_ws, size_t ws_size,
                              hipStream_t stream)
{
    const float* query = (const float*)d_in[0];
    const float* key   = (const float*)d_in[1];
    const float* value = (const float*)d_in[2];
    // d_in[3] = mask (tril causal) -- implemented analytically
    const float* Wq = (const float*)d_in[4];
    const float* bq = (const float*)d_in[5];
    const float* Wk = (const float*)d_in[6];
    const float* bk = (const float*)d_in[7];
    const float* Wv = (const float*)d_in[8];
    const float* bv = (const float*)d_in[9];
    const float* Wo = (const float*)d_in[10];
    const float* bo = (const float*)d_in[11];

    const long n_elem = (long)B_DIM * S_DIM * D_DIM;  // 4,194,304
    float* Qb   = (float*)d_ws;
    float* Kb   = Qb + n_elem;
    float* Vb   = Kb + n_elem;
    float* CTXb = Vb + n_elem;

    dim3 ggrid(D_DIM / BN, (B_DIM * S_DIM) / BM);  // (8, 32)
    gemm_bias_kernel<<<ggrid, 256, 0, stream>>>(query, Wq, bq, Qb);
    gemm_bias_kernel<<<ggrid, 256, 0, stream>>>(key,   Wk, bk, Kb);
    gemm_bias_kernel<<<ggrid, 256, 0, stream>>>(value, Wv, bv, Vb);

    rope_kernel<<<dim3(B_DIM * S_DIM, 2), 256, 0, stream>>>(Qb, Kb);

    attn_kernel<<<dim3(S_DIM / 64, H_DIM, B_DIM), 256, 0, stream>>>(Qb, Kb, Vb, CTXb);

    gemm_bias_kernel<<<ggrid, 256, 0, stream>>>(CTXb, Wo, bo, (float*)d_out);
}

// Round 2
// 455.957 us; speedup vs baseline: 2.0557x; 2.0557x over previous
//
#include <hip/hip_runtime.h>
#include <hip/hip_bf16.h>
#include <math.h>

#define B_DIM 4
#define S_DIM 1024
#define D_DIM 1024
#define H_DIM 16
#define HD_DIM 64
#define M_TOT (B_DIM * S_DIM)   // 4096

typedef short short8 __attribute__((ext_vector_type(8)));
typedef float f32x4 __attribute__((ext_vector_type(4)));

// ---------------------------------------------------------------------------
// fp32 -> bf16 conversion (4 elems/thread)
// ---------------------------------------------------------------------------
__global__ __launch_bounds__(256) void f32_to_bf16_kernel(
    const float* __restrict__ src, __hip_bfloat16* __restrict__ dst)
{
    const int base = (blockIdx.x * 256 + threadIdx.x) * 4;
    float4 v = *(const float4*)(src + base);
    __hip_bfloat16 o[4];
    o[0] = __float2bfloat16(v.x);
    o[1] = __float2bfloat16(v.y);
    o[2] = __float2bfloat16(v.z);
    o[3] = __float2bfloat16(v.w);
    *(uint2*)(dst + base) = *(uint2*)o;
}

// ---------------------------------------------------------------------------
// Transpose 1024x1024 fp32 W -> bf16 Wt (N,K layout)
// 32x32 tiles, 256 threads.
// ---------------------------------------------------------------------------
__global__ __launch_bounds__(256) void transpose_to_bf16_kernel(
    const float* __restrict__ W, __hip_bfloat16* __restrict__ Wt)
{
    __shared__ float tile[32][33];
    const int tid = threadIdx.x;
    const int r = tid >> 3;            // 0..31
    const int c4 = (tid & 7) * 4;      // 0..28

    float4 v = *(const float4*)&W[(long)(blockIdx.y * 32 + r) * D_DIM + blockIdx.x * 32 + c4];
    tile[r][c4 + 0] = v.x;
    tile[r][c4 + 1] = v.y;
    tile[r][c4 + 2] = v.z;
    tile[r][c4 + 3] = v.w;
    __syncthreads();

    // write transposed: Wt[col][row], 4 consecutive rows per thread
    __hip_bfloat16 o[4];
    o[0] = __float2bfloat16(tile[c4 + 0][r]);
    o[1] = __float2bfloat16(tile[c4 + 1][r]);
    o[2] = __float2bfloat16(tile[c4 + 2][r]);
    o[3] = __float2bfloat16(tile[c4 + 3][r]);
    *(uint2*)&Wt[(long)(blockIdx.x * 32 + r) * D_DIM + blockIdx.y * 32 + c4] = *(uint2*)o;
}

// ---------------------------------------------------------------------------
// bf16 MFMA GEMM (m97 structure): Out(M,N) = X(M,K) @ Wt(N,K)^T + bias
// 128x128 tile, BK=32, 256 threads = 4 waves, each wave does 64x64.
// Staging via global_load_lds width=16. fp32 output.
// M=4096, N=K=1024 fixed.
// ---------------------------------------------------------------------------
__device__ inline void gload_lds16(const void* gsrc, void* lds)
{
    __builtin_amdgcn_global_load_lds(
        (const __attribute__((address_space(1))) unsigned int*)gsrc,
        (__attribute__((address_space(3))) unsigned int*)lds, 16, 0, 0);
}

__global__ __launch_bounds__(256) void gemm_mfma_kernel(
    const __hip_bfloat16* __restrict__ X,   // (4096,1024) bf16 row-major
    const __hip_bfloat16* __restrict__ Wt,  // (1024,1024) bf16, (N,K) layout
    const float* __restrict__ bias,
    float* __restrict__ Out)                // (4096,1024) fp32
{
    __shared__ __align__(16) __hip_bfloat16 Al[128][32];  // 8 KB
    __shared__ __align__(16) __hip_bfloat16 Bl[128][32];  // 8 KB

    const int tid = threadIdx.x;
    const int l = tid & 63;
    const int w = tid >> 6;
    const int m0 = blockIdx.y * 128;
    const int n0 = blockIdx.x * 128;

    // staging mapping: per wave w, round r: rows r*64 + w*16 + l/4, k-chunk (l&3)*8
    const int srow = w * 16 + (l >> 2);
    const int skc = (l & 3) * 8;
    const __hip_bfloat16* Abase = X + (long)(m0 + srow) * D_DIM + skc;
    const __hip_bfloat16* Bbase = Wt + (long)(n0 + srow) * D_DIM + skc;
    char* ldsA0 = (char*)&Al[0][0] + w * 1024;
    char* ldsB0 = (char*)&Bl[0][0] + w * 1024;

    // fragment mapping
    const int lrow = l & 15;
    const int kg = l >> 4;
    const int wr = (w >> 1) * 64;
    const int wc = (w & 1) * 64;

    f32x4 acc[4][4];
#pragma unroll
    for (int i = 0; i < 4; ++i)
#pragma unroll
        for (int j = 0; j < 4; ++j) acc[i][j] = (f32x4){0.f, 0.f, 0.f, 0.f};

    for (int k0 = 0; k0 < D_DIM; k0 += 32) {
        __syncthreads();   // previous iter's readers done before overwrite
        gload_lds16(Abase + k0, ldsA0);
        gload_lds16(Abase + 64 * D_DIM + k0, ldsA0 + 4096);
        gload_lds16(Bbase + k0, ldsB0);
        gload_lds16(Bbase + 64 * D_DIM + k0, ldsB0 + 4096);
        __syncthreads();   // compiler emits vmcnt(0) drain before barrier

        short8 af[4], bf[4];
#pragma unroll
        for (int i = 0; i < 4; ++i)
            af[i] = *(const short8*)&Al[wr + i * 16 + lrow][kg * 8];
#pragma unroll
        for (int j = 0; j < 4; ++j)
            bf[j] = *(const short8*)&Bl[wc + j * 16 + lrow][kg * 8];
#pragma unroll
        for (int i = 0; i < 4; ++i)
#pragma unroll
            for (int j = 0; j < 4; ++j)
                acc[i][j] = __builtin_amdgcn_mfma_f32_16x16x32_bf16(
                    af[i], bf[j], acc[i][j], 0, 0, 0);
    }

    // epilogue: C/D layout col=lane&15, row=(lane>>4)*4+reg  [m89-verified]
#pragma unroll
    for (int i = 0; i < 4; ++i) {
#pragma unroll
        for (int j = 0; j < 4; ++j) {
            const int col = n0 + wc + j * 16 + lrow;
            const float bv = bias[col];
            const int rbase = m0 + wr + i * 16 + kg * 4;
#pragma unroll
            for (int r = 0; r < 4; ++r)
                Out[(long)(rbase + r) * D_DIM + col] = acc[i][j][r] + bv;
        }
    }
}

// ---------------------------------------------------------------------------
// RoPE (in-place), interleaved-input -> split-output variant (fp32)
// ---------------------------------------------------------------------------
__global__ __launch_bounds__(256) void rope_kernel(float* Q, float* K)
{
    const int row = blockIdx.x;            // 0..B*S-1
    const int pos = row & (S_DIM - 1);
    float* buf = ((blockIdx.y == 0) ? Q : K) + (long)row * D_DIM;
    const int tid = threadIdx.x;

    float o1[2], o2[2];
    int i1[2], i2[2];
#pragma unroll
    for (int it = 0; it < 2; ++it) {
        int p = tid + it * 256;            // pair id 0..511
        int h = p >> 5;
        int i = p & 31;
        float x1 = buf[h * 64 + 2 * i];
        float x2 = buf[h * 64 + 2 * i + 1];
        float inv = powf(10000.0f, -(float)(2 * i) / 64.0f);
        float ang = (float)pos * inv;
        float s, c;
        sincosf(ang, &s, &c);
        o1[it] = x1 * c - x2 * s;
        o2[it] = x1 * s + x2 * c;
        i1[it] = h * 64 + i;
        i2[it] = h * 64 + i + 32;
    }
    __syncthreads();
#pragma unroll
    for (int it = 0; it < 2; ++it) {
        buf[i1[it]] = o1[it];
        buf[i2[it]] = o2[it];
    }
}

// ---------------------------------------------------------------------------
// Flash-style causal attention, fp32 (unchanged from round 1).
// ---------------------------------------------------------------------------
#define APAD 68

__global__ __launch_bounds__(256) void attn_kernel(
    const float* __restrict__ Q, const float* __restrict__ K,
    const float* __restrict__ V, float* __restrict__ CTX)
{
    __shared__ float Qt[HD_DIM][APAD];
    __shared__ float Kt[HD_DIM][APAD];
    __shared__ float Vs[64][APAD];
    __shared__ float Pt[64][APAD];
    __shared__ float alphaS[64];
    __shared__ float lS[64];

    const int tid = threadIdx.x;
    const int qt = blockIdx.x;
    const int h  = blockIdx.y;
    const int b  = blockIdx.z;

    const int ty = tid >> 4, tx = tid & 15;
    const int qr = tid >> 2, ks = tid & 3;

    const long head_off = (long)h * HD_DIM;
    const long q_base = ((long)(b * S_DIM + qt * 64)) * D_DIM + head_off;

#pragma unroll
    for (int it = 0; it < 4; ++it) {
        int r = ty + 16 * it;
        float4 v = *(const float4*)&Q[q_base + (long)r * D_DIM + tx * 4];
        Qt[tx * 4 + 0][r] = v.x;
        Qt[tx * 4 + 1][r] = v.y;
        Qt[tx * 4 + 2][r] = v.z;
        Qt[tx * 4 + 3][r] = v.w;
    }

    float m_run = -1e30f, l_run = 0.f;
    float acc[4][4];
#pragma unroll
    for (int i = 0; i < 4; ++i)
#pragma unroll
        for (int j = 0; j < 4; ++j) acc[i][j] = 0.f;

    for (int kt = 0; kt <= qt; ++kt) {
        const long k_base = ((long)(b * S_DIM + kt * 64)) * D_DIM + head_off;
        __syncthreads();
#pragma unroll
        for (int it = 0; it < 4; ++it) {
            int r = ty + 16 * it;
            float4 kv = *(const float4*)&K[k_base + (long)r * D_DIM + tx * 4];
            Kt[tx * 4 + 0][r] = kv.x;
            Kt[tx * 4 + 1][r] = kv.y;
            Kt[tx * 4 + 2][r] = kv.z;
            Kt[tx * 4 + 3][r] = kv.w;
            float4 vv = *(const float4*)&V[k_base + (long)r * D_DIM + tx * 4];
            *(float4*)&Vs[r][tx * 4] = vv;
        }
        __syncthreads();

        float sc[4][4];
#pragma unroll
        for (int i = 0; i < 4; ++i)
#pragma unroll
            for (int j = 0; j < 4; ++j) sc[i][j] = 0.f;
#pragma unroll 4
        for (int dd = 0; dd < HD_DIM; ++dd) {
            float4 qa = *(const float4*)&Qt[dd][ty * 4];
            float4 ka = *(const float4*)&Kt[dd][tx * 4];
            float aa[4] = {qa.x, qa.y, qa.z, qa.w};
            float bb[4] = {ka.x, ka.y, ka.z, ka.w};
#pragma unroll
            for (int i = 0; i < 4; ++i)
#pragma unroll
                for (int j = 0; j < 4; ++j)
                    sc[i][j] = fmaf(aa[i], bb[j], sc[i][j]);
        }
        const bool diag = (kt == qt);
#pragma unroll
        for (int i = 0; i < 4; ++i) {
            int ql = ty * 4 + i;
#pragma unroll
            for (int j = 0; j < 4; ++j) {
                int kl = tx * 4 + j;
                float v = sc[i][j] * 0.125f;
                if (diag && kl > ql) v = -1e30f;
                Pt[kl][ql] = v;
            }
        }
        __syncthreads();

        float pv[16];
#pragma unroll
        for (int j = 0; j < 16; ++j) pv[j] = Pt[ks * 16 + j][qr];
        float mp = -1e30f;
#pragma unroll
        for (int j = 0; j < 16; ++j) mp = fmaxf(mp, pv[j]);
        mp = fmaxf(mp, __shfl_xor(mp, 1));
        mp = fmaxf(mp, __shfl_xor(mp, 2));
        float mnew = fmaxf(m_run, mp);
        float alpha = __expf(m_run - mnew);
        float lp = 0.f;
#pragma unroll
        for (int j = 0; j < 16; ++j) {
            float p = __expf(pv[j] - mnew);
            Pt[ks * 16 + j][qr] = p;
            lp += p;
        }
        lp += __shfl_xor(lp, 1);
        lp += __shfl_xor(lp, 2);
        l_run = l_run * alpha + lp;
        m_run = mnew;
        if (ks == 0) alphaS[qr] = alpha;
        __syncthreads();

#pragma unroll
        for (int i = 0; i < 4; ++i) {
            float al = alphaS[ty * 4 + i];
#pragma unroll
            for (int j = 0; j < 4; ++j) acc[i][j] *= al;
        }
#pragma unroll 4
        for (int k = 0; k < 64; ++k) {
            float4 pa = *(const float4*)&Pt[k][ty * 4];
            float4 vb = *(const float4*)&Vs[k][tx * 4];
            float aa[4] = {pa.x, pa.y, pa.z, pa.w};
            float bb[4] = {vb.x, vb.y, vb.z, vb.w};
#pragma unroll
            for (int i = 0; i < 4; ++i)
#pragma unroll
                for (int j = 0; j < 4; ++j)
                    acc[i][j] = fmaf(aa[i], bb[j], acc[i][j]);
        }
    }

    if (ks == 0) lS[qr] = l_run;
    __syncthreads();

#pragma unroll
    for (int i = 0; i < 4; ++i) {
        int ql = ty * 4 + i;
        float inv_l = 1.0f / lS[ql];
        float4 o;
        o.x = acc[i][0] * inv_l;
        o.y = acc[i][1] * inv_l;
        o.z = acc[i][2] * inv_l;
        o.w = acc[i][3] * inv_l;
        *(float4*)&CTX[q_base + (long)ql * D_DIM + tx * 4] = o;
    }
}

// ---------------------------------------------------------------------------
extern "C" void kernel_launch(void* const* d_in, const int* in_sizes, int n_in,
                              void* d_out, int out_size, void* d_ws, size_t ws_size,
                              hipStream_t stream)
{
    const float* query = (const float*)d_in[0];
    const float* key   = (const float*)d_in[1];
    const float* value = (const float*)d_in[2];
    const float* Wq = (const float*)d_in[4];
    const float* bq = (const float*)d_in[5];
    const float* Wk = (const float*)d_in[6];
    const float* bk = (const float*)d_in[7];
    const float* Wv = (const float*)d_in[8];
    const float* bv = (const float*)d_in[9];
    const float* Wo = (const float*)d_in[10];
    const float* bo = (const float*)d_in[11];

    char* wsb = (char*)d_ws;
    float* Qb   = (float*)(wsb);                      // 16 MB
    float* Kb   = (float*)(wsb + (16L << 20));        // 16 MB
    float* Vb   = (float*)(wsb + (32L << 20));        // 16 MB
    float* CTXb = (float*)(wsb + (48L << 20));        // 16 MB
    __hip_bfloat16* Xq  = (__hip_bfloat16*)(wsb + (64L << 20));  // 8 MB
    __hip_bfloat16* Xk  = (__hip_bfloat16*)(wsb + (72L << 20));  // 8 MB
    __hip_bfloat16* Xv  = (__hip_bfloat16*)(wsb + (80L << 20));  // 8 MB
    __hip_bfloat16* WtQ = (__hip_bfloat16*)(wsb + (88L << 20));  // 2 MB
    __hip_bfloat16* WtK = (__hip_bfloat16*)(wsb + (90L << 20));
    __hip_bfloat16* WtV = (__hip_bfloat16*)(wsb + (92L << 20));
    __hip_bfloat16* WtO = (__hip_bfloat16*)(wsb + (94L << 20));
    __hip_bfloat16* CTXbf = (__hip_bfloat16*)(wsb + (64L << 20)); // reuse Xq slot

    const int conv_blocks = (M_TOT * D_DIM) / (256 * 4);   // 4096

    // convert activations to bf16
    f32_to_bf16_kernel<<<conv_blocks, 256, 0, stream>>>(query, Xq);
    f32_to_bf16_kernel<<<conv_blocks, 256, 0, stream>>>(key,   Xk);
    f32_to_bf16_kernel<<<conv_blocks, 256, 0, stream>>>(value, Xv);

    // transpose+convert weights
    dim3 tgrid(32, 32);
    transpose_to_bf16_kernel<<<tgrid, 256, 0, stream>>>(Wq, WtQ);
    transpose_to_bf16_kernel<<<tgrid, 256, 0, stream>>>(Wk, WtK);
    transpose_to_bf16_kernel<<<tgrid, 256, 0, stream>>>(Wv, WtV);
    transpose_to_bf16_kernel<<<tgrid, 256, 0, stream>>>(Wo, WtO);

    // projections (bf16 MFMA, fp32 out)
    dim3 ggrid(D_DIM / 128, M_TOT / 128);   // (8, 32)
    gemm_mfma_kernel<<<ggrid, 256, 0, stream>>>(Xq, WtQ, bq, Qb);
    gemm_mfma_kernel<<<ggrid, 256, 0, stream>>>(Xk, WtK, bk, Kb);
    gemm_mfma_kernel<<<ggrid, 256, 0, stream>>>(Xv, WtV, bv, Vb);

    rope_kernel<<<dim3(B_DIM * S_DIM, 2), 256, 0, stream>>>(Qb, Kb);

    attn_kernel<<<dim3(S_DIM / 64, H_DIM, B_DIM), 256, 0, stream>>>(Qb, Kb, Vb, CTXb);

    // ctx -> bf16, final projection
    f32_to_bf16_kernel<<<conv_blocks, 256, 0, stream>>>(CTXb, CTXbf);
    gemm_mfma_kernel<<<ggrid, 256, 0, stream>>>(CTXbf, WtO, bo, (float*)d_out);
}

// Round 3
// 214.401 us; speedup vs baseline: 4.3718x; 2.1267x over previous
//
#include <hip/hip_runtime.h>
#include <hip/hip_bf16.h>
#include <math.h>

#define B_DIM 4
#define S_DIM 1024
#define D_DIM 1024
#define H_DIM 16
#define HD_DIM 64
#define M_TOT (B_DIM * S_DIM)   // 4096

typedef short short8 __attribute__((ext_vector_type(8)));
typedef float f32x4 __attribute__((ext_vector_type(4)));

// ---------------------------------------------------------------------------
// fp32 -> bf16 conversion (4 elems/thread)
// ---------------------------------------------------------------------------
__global__ __launch_bounds__(256) void f32_to_bf16_kernel(
    const float* __restrict__ src, __hip_bfloat16* __restrict__ dst)
{
    const int base = (blockIdx.x * 256 + threadIdx.x) * 4;
    float4 v = *(const float4*)(src + base);
    __hip_bfloat16 o[4];
    o[0] = __float2bfloat16(v.x);
    o[1] = __float2bfloat16(v.y);
    o[2] = __float2bfloat16(v.z);
    o[3] = __float2bfloat16(v.w);
    *(uint2*)(dst + base) = *(uint2*)o;
}

// ---------------------------------------------------------------------------
// Transpose 1024x1024 fp32 W -> bf16 Wt (N,K layout)
// ---------------------------------------------------------------------------
__global__ __launch_bounds__(256) void transpose_to_bf16_kernel(
    const float* __restrict__ W, __hip_bfloat16* __restrict__ Wt)
{
    __shared__ float tile[32][33];
    const int tid = threadIdx.x;
    const int r = tid >> 3;            // 0..31
    const int c4 = (tid & 7) * 4;      // 0..28

    float4 v = *(const float4*)&W[(long)(blockIdx.y * 32 + r) * D_DIM + blockIdx.x * 32 + c4];
    tile[r][c4 + 0] = v.x;
    tile[r][c4 + 1] = v.y;
    tile[r][c4 + 2] = v.z;
    tile[r][c4 + 3] = v.w;
    __syncthreads();

    __hip_bfloat16 o[4];
    o[0] = __float2bfloat16(tile[c4 + 0][r]);
    o[1] = __float2bfloat16(tile[c4 + 1][r]);
    o[2] = __float2bfloat16(tile[c4 + 2][r]);
    o[3] = __float2bfloat16(tile[c4 + 3][r]);
    *(uint2*)&Wt[(long)(blockIdx.x * 32 + r) * D_DIM + blockIdx.y * 32 + c4] = *(uint2*)o;
}

// ---------------------------------------------------------------------------
// bf16 MFMA GEMM (m97 structure): Out(M,N) = X(M,K) @ Wt(N,K)^T + bias
// fp32 output variant.
// ---------------------------------------------------------------------------
__device__ inline void gload_lds16(const void* gsrc, void* lds)
{
    __builtin_amdgcn_global_load_lds(
        (const __attribute__((address_space(1))) unsigned int*)gsrc,
        (__attribute__((address_space(3))) unsigned int*)lds, 16, 0, 0);
}

__global__ __launch_bounds__(256) void gemm_mfma_kernel(
    const __hip_bfloat16* __restrict__ X,
    const __hip_bfloat16* __restrict__ Wt,
    const float* __restrict__ bias,
    float* __restrict__ Out)
{
    __shared__ __align__(16) __hip_bfloat16 Al[128][32];
    __shared__ __align__(16) __hip_bfloat16 Bl[128][32];

    const int tid = threadIdx.x;
    const int l = tid & 63;
    const int w = tid >> 6;
    const int m0 = blockIdx.y * 128;
    const int n0 = blockIdx.x * 128;

    const int srow = w * 16 + (l >> 2);
    const int skc = (l & 3) * 8;
    const __hip_bfloat16* Abase = X + (long)(m0 + srow) * D_DIM + skc;
    const __hip_bfloat16* Bbase = Wt + (long)(n0 + srow) * D_DIM + skc;
    char* ldsA0 = (char*)&Al[0][0] + w * 1024;
    char* ldsB0 = (char*)&Bl[0][0] + w * 1024;

    const int lrow = l & 15;
    const int kg = l >> 4;
    const int wr = (w >> 1) * 64;
    const int wc = (w & 1) * 64;

    f32x4 acc[4][4];
#pragma unroll
    for (int i = 0; i < 4; ++i)
#pragma unroll
        for (int j = 0; j < 4; ++j) acc[i][j] = (f32x4){0.f, 0.f, 0.f, 0.f};

    for (int k0 = 0; k0 < D_DIM; k0 += 32) {
        __syncthreads();
        gload_lds16(Abase + k0, ldsA0);
        gload_lds16(Abase + 64 * D_DIM + k0, ldsA0 + 4096);
        gload_lds16(Bbase + k0, ldsB0);
        gload_lds16(Bbase + 64 * D_DIM + k0, ldsB0 + 4096);
        __syncthreads();

        short8 af[4], bf[4];
#pragma unroll
        for (int i = 0; i < 4; ++i)
            af[i] = *(const short8*)&Al[wr + i * 16 + lrow][kg * 8];
#pragma unroll
        for (int j = 0; j < 4; ++j)
            bf[j] = *(const short8*)&Bl[wc + j * 16 + lrow][kg * 8];
#pragma unroll
        for (int i = 0; i < 4; ++i)
#pragma unroll
            for (int j = 0; j < 4; ++j)
                acc[i][j] = __builtin_amdgcn_mfma_f32_16x16x32_bf16(
                    af[i], bf[j], acc[i][j], 0, 0, 0);
    }

#pragma unroll
    for (int i = 0; i < 4; ++i) {
#pragma unroll
        for (int j = 0; j < 4; ++j) {
            const int col = n0 + wc + j * 16 + lrow;
            const float bv = bias[col];
            const int rbase = m0 + wr + i * 16 + kg * 4;
#pragma unroll
            for (int r = 0; r < 4; ++r)
                Out[(long)(rbase + r) * D_DIM + col] = acc[i][j][r] + bv;
        }
    }
}

// ---------------------------------------------------------------------------
// Same GEMM, but writes bf16 V^T: Vt[b][h][d][s]  (s contiguous)
// ---------------------------------------------------------------------------
__global__ __launch_bounds__(256) void gemm_mfma_vt_kernel(
    const __hip_bfloat16* __restrict__ X,
    const __hip_bfloat16* __restrict__ Wt,
    const float* __restrict__ bias,
    __hip_bfloat16* __restrict__ VtOut)
{
    __shared__ __align__(16) __hip_bfloat16 Al[128][32];
    __shared__ __align__(16) __hip_bfloat16 Bl[128][32];

    const int tid = threadIdx.x;
    const int l = tid & 63;
    const int w = tid >> 6;
    const int m0 = blockIdx.y * 128;
    const int n0 = blockIdx.x * 128;

    const int srow = w * 16 + (l >> 2);
    const int skc = (l & 3) * 8;
    const __hip_bfloat16* Abase = X + (long)(m0 + srow) * D_DIM + skc;
    const __hip_bfloat16* Bbase = Wt + (long)(n0 + srow) * D_DIM + skc;
    char* ldsA0 = (char*)&Al[0][0] + w * 1024;
    char* ldsB0 = (char*)&Bl[0][0] + w * 1024;

    const int lrow = l & 15;
    const int kg = l >> 4;
    const int wr = (w >> 1) * 64;
    const int wc = (w & 1) * 64;

    f32x4 acc[4][4];
#pragma unroll
    for (int i = 0; i < 4; ++i)
#pragma unroll
        for (int j = 0; j < 4; ++j) acc[i][j] = (f32x4){0.f, 0.f, 0.f, 0.f};

    for (int k0 = 0; k0 < D_DIM; k0 += 32) {
        __syncthreads();
        gload_lds16(Abase + k0, ldsA0);
        gload_lds16(Abase + 64 * D_DIM + k0, ldsA0 + 4096);
        gload_lds16(Bbase + k0, ldsB0);
        gload_lds16(Bbase + 64 * D_DIM + k0, ldsB0 + 4096);
        __syncthreads();

        short8 af[4], bf[4];
#pragma unroll
        for (int i = 0; i < 4; ++i)
            af[i] = *(const short8*)&Al[wr + i * 16 + lrow][kg * 8];
#pragma unroll
        for (int j = 0; j < 4; ++j)
            bf[j] = *(const short8*)&Bl[wc + j * 16 + lrow][kg * 8];
#pragma unroll
        for (int i = 0; i < 4; ++i)
#pragma unroll
            for (int j = 0; j < 4; ++j)
                acc[i][j] = __builtin_amdgcn_mfma_f32_16x16x32_bf16(
                    af[i], bf[j], acc[i][j], 0, 0, 0);
    }

    // epilogue: V^T[b][h][d][s] bf16, 4 consecutive s per lane (8B store)
#pragma unroll
    for (int i = 0; i < 4; ++i) {
#pragma unroll
        for (int j = 0; j < 4; ++j) {
            const int col = n0 + wc + j * 16 + lrow;   // n = h*64 + d
            const float bv = bias[col];
            const int hh = col >> 6, dd = col & 63;
            const int rbase = m0 + wr + i * 16 + kg * 4;  // m = b*1024 + s
            const int bb = rbase >> 10, s0 = rbase & 1023;
            __hip_bfloat16 o[4];
#pragma unroll
            for (int r = 0; r < 4; ++r)
                o[r] = __float2bfloat16(acc[i][j][r] + bv);
            *(uint2*)&VtOut[((long)((bb * H_DIM + hh) * HD_DIM + dd)) * S_DIM + s0] = *(uint2*)o;
        }
    }
}

// ---------------------------------------------------------------------------
// RoPE: fp32 in -> bf16 out, interleaved-input -> split-output.
// thread handles 4 consecutive pairs of one head.
// ---------------------------------------------------------------------------
__global__ __launch_bounds__(256) void rope_bf16_kernel(
    const float* __restrict__ Qf, const float* __restrict__ Kf,
    __hip_bfloat16* __restrict__ Qb, __hip_bfloat16* __restrict__ Kb)
{
    const long t = (long)blockIdx.x * 256 + threadIdx.x;  // 0..512K-1
    const int row = (int)(t >> 7);
    const int slot = (int)(t & 127);
    const int hh = slot >> 3;
    const int p0 = (slot & 7) * 4;
    const int pos = row & (S_DIM - 1);

    const float* src = ((blockIdx.y == 0) ? Qf : Kf) + (long)row * D_DIM + hh * HD_DIM;
    __hip_bfloat16* dst = ((blockIdx.y == 0) ? Qb : Kb) + (long)row * D_DIM + hh * HD_DIM;

    float4 a = *(const float4*)&src[2 * p0];
    float4 bq = *(const float4*)&src[2 * p0 + 4];
    float x1[4] = {a.x, a.z, bq.x, bq.z};
    float x2[4] = {a.y, a.w, bq.y, bq.w};
    __hip_bfloat16 o1[4], o2[4];
#pragma unroll
    for (int j = 0; j < 4; ++j) {
        int i = p0 + j;
        float inv = powf(10000.0f, -(float)(2 * i) / 64.0f);
        float ang = (float)pos * inv;
        float s, c;
        sincosf(ang, &s, &c);
        o1[j] = __float2bfloat16(x1[j] * c - x2[j] * s);
        o2[j] = __float2bfloat16(x1[j] * s + x2[j] * c);
    }
    *(uint2*)&dst[p0]      = *(uint2*)o1;
    *(uint2*)&dst[p0 + 32] = *(uint2*)o2;
}

// ---------------------------------------------------------------------------
// MFMA flash attention (causal). Block = (qt,h,b): 128 q-rows, 4 waves x 32.
// K staged [k][d], V^T staged [d][k], both padded. P per-wave in LDS.
// ---------------------------------------------------------------------------
#define KPAD 72
#define SCALE 0.125f

__global__ __launch_bounds__(256) void attn_mfma_kernel(
    const __hip_bfloat16* __restrict__ Q,   // [4096][1024] bf16 (rope'd)
    const __hip_bfloat16* __restrict__ K,   // [4096][1024] bf16 (rope'd)
    const __hip_bfloat16* __restrict__ Vt,  // [b][h][64][1024] bf16
    __hip_bfloat16* __restrict__ CTX)       // [4096][1024] bf16
{
    __shared__ __align__(16) __hip_bfloat16 Kl[64][KPAD];
    __shared__ __align__(16) __hip_bfloat16 Vl[64][KPAD];
    __shared__ __align__(16) __hip_bfloat16 Pl[4][32][KPAD];

    const int tid = threadIdx.x;
    const int l = tid & 63;
    const int w = tid >> 6;
    const int qt = blockIdx.x, h = blockIdx.y, b = blockIdx.z;
    const int lrow = l & 15;
    const int kg = l >> 4;

    const int q0w = qt * 128 + w * 32;
    const long qrow_base = (long)b * S_DIM + q0w;

    // Q fragments, held in registers for the whole kernel
    short8 qf[2][2];
#pragma unroll
    for (int m = 0; m < 2; ++m)
#pragma unroll
        for (int ks = 0; ks < 2; ++ks)
            qf[m][ks] = *(const short8*)&Q[(qrow_base + m * 16 + lrow) * D_DIM +
                                           h * HD_DIM + ks * 32 + kg * 8];

    f32x4 ctx[2][4];
#pragma unroll
    for (int m = 0; m < 2; ++m)
#pragma unroll
        for (int d = 0; d < 4; ++d) ctx[m][d] = (f32x4){0.f, 0.f, 0.f, 0.f};
    float mrun[2][4], lrun[2][4];
#pragma unroll
    for (int m = 0; m < 2; ++m)
#pragma unroll
        for (int r = 0; r < 4; ++r) { mrun[m][r] = -1e30f; lrun[m][r] = 0.f; }

    // staging mapping: thread -> row tid>>2, 32B chunk (tid&3)
    const int sr = tid >> 2;
    const int sc = (tid & 3) * 16;
    const __hip_bfloat16* Kg = K + ((long)b * S_DIM + sr) * D_DIM + h * HD_DIM + sc;
    const __hip_bfloat16* Vg = Vt + ((long)((b * H_DIM + h) * HD_DIM) + sr) * S_DIM + sc;

    const int ktmax = 2 * qt + 1;
    for (int kt = 0; kt <= ktmax; ++kt) {
        __syncthreads();
        {
            const __hip_bfloat16* kp = Kg + (long)kt * 64 * D_DIM;
            short8 k0 = *(const short8*)kp;
            short8 k1 = *(const short8*)(kp + 8);
            const __hip_bfloat16* vp = Vg + kt * 64;
            short8 v0 = *(const short8*)vp;
            short8 v1 = *(const short8*)(vp + 8);
            *(short8*)&Kl[sr][sc] = k0;
            *(short8*)&Kl[sr][sc + 8] = k1;
            *(short8*)&Vl[sr][sc] = v0;
            *(short8*)&Vl[sr][sc + 8] = v1;
        }
        __syncthreads();

        if (kt * 64 > q0w + 31) continue;   // fully masked for this wave

        // ---- scores: S = Q K^T
        f32x4 sac[2][4];
#pragma unroll
        for (int m = 0; m < 2; ++m)
#pragma unroll
            for (int nt = 0; nt < 4; ++nt) sac[m][nt] = (f32x4){0.f, 0.f, 0.f, 0.f};

        short8 kf[4][2];
#pragma unroll
        for (int nt = 0; nt < 4; ++nt)
#pragma unroll
            for (int ks = 0; ks < 2; ++ks)
                kf[nt][ks] = *(const short8*)&Kl[nt * 16 + lrow][ks * 32 + kg * 8];
#pragma unroll
        for (int m = 0; m < 2; ++m)
#pragma unroll
            for (int nt = 0; nt < 4; ++nt)
#pragma unroll
                for (int ks = 0; ks < 2; ++ks)
                    sac[m][nt] = __builtin_amdgcn_mfma_f32_16x16x32_bf16(
                        qf[m][ks], kf[nt][ks], sac[m][nt], 0, 0, 0);

        // ---- online softmax (rows: q = q0w + m*16 + kg*4 + r; col = lane&15)
        const bool partial = (kt * 64 + 63 > q0w);
#pragma unroll
        for (int m = 0; m < 2; ++m) {
#pragma unroll
            for (int r = 0; r < 4; ++r) {
                const int qg = q0w + m * 16 + kg * 4 + r;
                float s[4];
#pragma unroll
                for (int nt = 0; nt < 4; ++nt) {
                    s[nt] = sac[m][nt][r] * SCALE;
                    if (partial && (kt * 64 + nt * 16 + lrow > qg)) s[nt] = -1e30f;
                }
                float mx = fmaxf(fmaxf(s[0], s[1]), fmaxf(s[2], s[3]));
                mx = fmaxf(mx, __shfl_xor(mx, 1));
                mx = fmaxf(mx, __shfl_xor(mx, 2));
                mx = fmaxf(mx, __shfl_xor(mx, 4));
                mx = fmaxf(mx, __shfl_xor(mx, 8));
                const float mnew = fmaxf(mrun[m][r], mx);
                float p[4], sum = 0.f;
#pragma unroll
                for (int nt = 0; nt < 4; ++nt) {
                    p[nt] = __expf(s[nt] - mnew);
                    sum += p[nt];
                }
                sum += __shfl_xor(sum, 1);
                sum += __shfl_xor(sum, 2);
                sum += __shfl_xor(sum, 4);
                sum += __shfl_xor(sum, 8);
                const float alpha = __expf(mrun[m][r] - mnew);
                mrun[m][r] = mnew;
                lrun[m][r] = lrun[m][r] * alpha + sum;
#pragma unroll
                for (int d = 0; d < 4; ++d) ctx[m][d][r] *= alpha;
#pragma unroll
                for (int nt = 0; nt < 4; ++nt)
                    Pl[w][m * 16 + kg * 4 + r][nt * 16 + lrow] = __float2bfloat16(p[nt]);
            }
        }

        // ---- PV: ctx += P V   (A = P[q][k], B = V^T[d][k])
        short8 vf[4][2];
#pragma unroll
        for (int dt = 0; dt < 4; ++dt)
#pragma unroll
            for (int ks = 0; ks < 2; ++ks)
                vf[dt][ks] = *(const short8*)&Vl[dt * 16 + lrow][ks * 32 + kg * 8];
#pragma unroll
        for (int m = 0; m < 2; ++m) {
            short8 pf[2];
#pragma unroll
            for (int ks = 0; ks < 2; ++ks)
                pf[ks] = *(const short8*)&Pl[w][m * 16 + lrow][ks * 32 + kg * 8];
#pragma unroll
            for (int dt = 0; dt < 4; ++dt)
#pragma unroll
                for (int ks = 0; ks < 2; ++ks)
                    ctx[m][dt] = __builtin_amdgcn_mfma_f32_16x16x32_bf16(
                        pf[ks], vf[dt][ks], ctx[m][dt], 0, 0, 0);
        }
    }

    // ---- epilogue: normalize and write bf16
#pragma unroll
    for (int m = 0; m < 2; ++m) {
#pragma unroll
        for (int r = 0; r < 4; ++r) {
            const float inv_l = 1.0f / lrun[m][r];
            const long row = (qrow_base + m * 16 + kg * 4 + r) * D_DIM + h * HD_DIM;
#pragma unroll
            for (int dt = 0; dt < 4; ++dt)
                CTX[row + dt * 16 + lrow] = __float2bfloat16(ctx[m][dt][r] * inv_l);
        }
    }
}

// ---------------------------------------------------------------------------
extern "C" void kernel_launch(void* const* d_in, const int* in_sizes, int n_in,
                              void* d_out, int out_size, void* d_ws, size_t ws_size,
                              hipStream_t stream)
{
    const float* query = (const float*)d_in[0];
    const float* key   = (const float*)d_in[1];
    const float* value = (const float*)d_in[2];
    const float* Wq = (const float*)d_in[4];
    const float* bq = (const float*)d_in[5];
    const float* Wk = (const float*)d_in[6];
    const float* bk = (const float*)d_in[7];
    const float* Wv = (const float*)d_in[8];
    const float* bv = (const float*)d_in[9];
    const float* Wo = (const float*)d_in[10];
    const float* bo = (const float*)d_in[11];

    char* wsb = (char*)d_ws;
    float*          Qb    = (float*)(wsb);                          // 16 MB fp32
    float*          Kb    = (float*)(wsb + (16L << 20));            // 16 MB fp32
    __hip_bfloat16* Xq    = (__hip_bfloat16*)(wsb + (32L << 20));   // 8 MB
    __hip_bfloat16* Xk    = (__hip_bfloat16*)(wsb + (40L << 20));   // 8 MB
    __hip_bfloat16* Xv    = (__hip_bfloat16*)(wsb + (48L << 20));   // 8 MB
    __hip_bfloat16* Qbf   = (__hip_bfloat16*)(wsb + (56L << 20));   // 8 MB
    __hip_bfloat16* Kbf   = (__hip_bfloat16*)(wsb + (64L << 20));   // 8 MB
    __hip_bfloat16* Vtb   = (__hip_bfloat16*)(wsb + (72L << 20));   // 8 MB
    __hip_bfloat16* CTXbf = (__hip_bfloat16*)(wsb + (80L << 20));   // 8 MB
    __hip_bfloat16* WtQ   = (__hip_bfloat16*)(wsb + (88L << 20));   // 2 MB
    __hip_bfloat16* WtK   = (__hip_bfloat16*)(wsb + (90L << 20));
    __hip_bfloat16* WtV   = (__hip_bfloat16*)(wsb + (92L << 20));
    __hip_bfloat16* WtO   = (__hip_bfloat16*)(wsb + (94L << 20));

    const int conv_blocks = (M_TOT * D_DIM) / (256 * 4);   // 4096

    f32_to_bf16_kernel<<<conv_blocks, 256, 0, stream>>>(query, Xq);
    f32_to_bf16_kernel<<<conv_blocks, 256, 0, stream>>>(key,   Xk);
    f32_to_bf16_kernel<<<conv_blocks, 256, 0, stream>>>(value, Xv);

    dim3 tgrid(32, 32);
    transpose_to_bf16_kernel<<<tgrid, 256, 0, stream>>>(Wq, WtQ);
    transpose_to_bf16_kernel<<<tgrid, 256, 0, stream>>>(Wk, WtK);
    transpose_to_bf16_kernel<<<tgrid, 256, 0, stream>>>(Wv, WtV);
    transpose_to_bf16_kernel<<<tgrid, 256, 0, stream>>>(Wo, WtO);

    dim3 ggrid(D_DIM / 128, M_TOT / 128);   // (8, 32)
    gemm_mfma_kernel<<<ggrid, 256, 0, stream>>>(Xq, WtQ, bq, Qb);
    gemm_mfma_kernel<<<ggrid, 256, 0, stream>>>(Xk, WtK, bk, Kb);
    gemm_mfma_vt_kernel<<<ggrid, 256, 0, stream>>>(Xv, WtV, bv, Vtb);

    rope_bf16_kernel<<<dim3(2048, 2), 256, 0, stream>>>(Qb, Kb, Qbf, Kbf);

    attn_mfma_kernel<<<dim3(S_DIM / 128, H_DIM, B_DIM), 256, 0, stream>>>(
        Qbf, Kbf, Vtb, CTXbf);

    gemm_mfma_kernel<<<ggrid, 256, 0, stream>>>(CTXbf, WtO, bo, (float*)d_out);
}

// Round 4
// 189.552 us; speedup vs baseline: 4.9450x; 1.1311x over previous
//
#include <hip/hip_runtime.h>
#include <hip/hip_bf16.h>
#include <math.h>

#define B_DIM 4
#define S_DIM 1024
#define D_DIM 1024
#define H_DIM 16
#define HD_DIM 64
#define M_TOT 4096

typedef short short8 __attribute__((ext_vector_type(8)));
typedef float f32x4 __attribute__((ext_vector_type(4)));

__device__ inline float bf2f(short u)
{
    return __uint_as_float(((unsigned)(unsigned short)u) << 16);
}

__device__ inline void gload_lds16(const void* gsrc, void* lds)
{
    __builtin_amdgcn_global_load_lds(
        (const __attribute__((address_space(1))) unsigned int*)gsrc,
        (__attribute__((address_space(3))) unsigned int*)lds, 16, 0, 0);
}

// ---------------------------------------------------------------------------
// RoPE cos/sin table: tab[0][pos][i] = cos, tab[1][pos][i] = sin  (1024 x 32)
// ---------------------------------------------------------------------------
__global__ __launch_bounds__(256) void rope_table_kernel(float* __restrict__ tab)
{
    const int t = blockIdx.x * 256 + threadIdx.x;   // 0..32767
    const int pos = t >> 5, i = t & 31;
    float inv = powf(10000.0f, -(float)(2 * i) / 64.0f);
    float ang = (float)pos * inv;
    float s, c;
    sincosf(ang, &s, &c);
    tab[t] = c;
    tab[32768 + t] = s;
}

// ---------------------------------------------------------------------------
// Fused 4x transpose 1024x1024 fp32 W -> bf16 Wt (N,K layout)
// ---------------------------------------------------------------------------
__global__ __launch_bounds__(256) void transpose4_to_bf16_kernel(
    const float* __restrict__ W0, const float* __restrict__ W1,
    const float* __restrict__ W2, const float* __restrict__ W3,
    __hip_bfloat16* __restrict__ T0, __hip_bfloat16* __restrict__ T1,
    __hip_bfloat16* __restrict__ T2, __hip_bfloat16* __restrict__ T3)
{
    const float* W = (blockIdx.z == 0) ? W0 : (blockIdx.z == 1) ? W1
                    : (blockIdx.z == 2) ? W2 : W3;
    __hip_bfloat16* T = (blockIdx.z == 0) ? T0 : (blockIdx.z == 1) ? T1
                       : (blockIdx.z == 2) ? T2 : T3;

    __shared__ float tile[32][33];
    const int tid = threadIdx.x;
    const int r = tid >> 3;
    const int c4 = (tid & 7) * 4;

    float4 v = *(const float4*)&W[(long)(blockIdx.y * 32 + r) * D_DIM + blockIdx.x * 32 + c4];
    tile[r][c4 + 0] = v.x;
    tile[r][c4 + 1] = v.y;
    tile[r][c4 + 2] = v.z;
    tile[r][c4 + 3] = v.w;
    __syncthreads();

    __hip_bfloat16 o[4];
    o[0] = __float2bfloat16(tile[c4 + 0][r]);
    o[1] = __float2bfloat16(tile[c4 + 1][r]);
    o[2] = __float2bfloat16(tile[c4 + 2][r]);
    o[3] = __float2bfloat16(tile[c4 + 3][r]);
    *(uint2*)&T[(long)(blockIdx.x * 32 + r) * D_DIM + blockIdx.y * 32 + c4] = *(uint2*)o;
}

// ---------------------------------------------------------------------------
// bf16 MFMA GEMM: Out(M,N) = X(M,K) @ Wt(N,K)^T + bias
// OUT_MODE: 0 = fp32 row-major, 1 = bf16 row-major, 2 = bf16 V^T [b][h][d][s]
// A_F32:    true  = X is fp32, converted during reg->LDS staging (padded LDS)
//           false = X is bf16, staged via global_load_lds (linear LDS)
// ---------------------------------------------------------------------------
template<int OUT_MODE, bool A_F32>
__global__ __launch_bounds__(256) void gemm_mfma_t(
    const void* __restrict__ Xv, const __hip_bfloat16* __restrict__ Wt,
    const float* __restrict__ bias, void* __restrict__ OutV)
{
    constexpr int APITCH = A_F32 ? 40 : 32;   // 80B rows when padded (16B-aligned)
    __shared__ __align__(16) __hip_bfloat16 Al[128][APITCH];
    __shared__ __align__(16) __hip_bfloat16 Bl[128][32];

    const int tid = threadIdx.x;
    const int l = tid & 63;
    const int w = tid >> 6;
    const int m0 = blockIdx.y * 128;
    const int n0 = blockIdx.x * 128;

    // B staging mapping (global_load_lds, verified)
    const int srow = w * 16 + (l >> 2);
    const int skc = (l & 3) * 8;
    const __hip_bfloat16* Bbase = Wt + (long)(n0 + srow) * D_DIM + skc;
    char* ldsB0 = (char*)&Bl[0][0] + w * 1024;

    // A staging mapping
    const float* Af = nullptr;
    const __hip_bfloat16* Abf = nullptr;
    char* ldsA0 = nullptr;
    int arow = 0, ak = 0;
    if constexpr (A_F32) {
        arow = tid >> 1;
        ak = (tid & 1) * 16;
        Af = (const float*)Xv + (long)(m0 + arow) * D_DIM + ak;
    } else {
        Abf = (const __hip_bfloat16*)Xv + (long)(m0 + srow) * D_DIM + skc;
        ldsA0 = (char*)&Al[0][0] + w * 1024;
    }

    const int lrow = l & 15;
    const int kg = l >> 4;
    const int wr = (w >> 1) * 64;
    const int wc = (w & 1) * 64;

    f32x4 acc[4][4];
#pragma unroll
    for (int i = 0; i < 4; ++i)
#pragma unroll
        for (int j = 0; j < 4; ++j) acc[i][j] = (f32x4){0.f, 0.f, 0.f, 0.f};

    for (int k0 = 0; k0 < D_DIM; k0 += 32) {
        __syncthreads();
        if constexpr (A_F32) {
            float4 f0 = *(const float4*)(Af + k0);
            float4 f1 = *(const float4*)(Af + k0 + 4);
            float4 f2 = *(const float4*)(Af + k0 + 8);
            float4 f3 = *(const float4*)(Af + k0 + 12);
            gload_lds16(Bbase + k0, ldsB0);
            gload_lds16(Bbase + 64 * D_DIM + k0, ldsB0 + 4096);
            float fa[16] = {f0.x, f0.y, f0.z, f0.w, f1.x, f1.y, f1.z, f1.w,
                            f2.x, f2.y, f2.z, f2.w, f3.x, f3.y, f3.z, f3.w};
            __attribute__((aligned(16))) __hip_bfloat16 ab[16];
#pragma unroll
            for (int i = 0; i < 16; ++i) ab[i] = __float2bfloat16(fa[i]);
            *(short8*)&Al[arow][ak]     = ((const short8*)ab)[0];
            *(short8*)&Al[arow][ak + 8] = ((const short8*)ab)[1];
        } else {
            gload_lds16(Abf + k0, ldsA0);
            gload_lds16(Abf + 64 * D_DIM + k0, ldsA0 + 4096);
            gload_lds16(Bbase + k0, ldsB0);
            gload_lds16(Bbase + 64 * D_DIM + k0, ldsB0 + 4096);
        }
        __syncthreads();

        short8 af[4], bf[4];
#pragma unroll
        for (int i = 0; i < 4; ++i)
            af[i] = *(const short8*)&Al[wr + i * 16 + lrow][kg * 8];
#pragma unroll
        for (int j = 0; j < 4; ++j)
            bf[j] = *(const short8*)&Bl[wc + j * 16 + lrow][kg * 8];
#pragma unroll
        for (int i = 0; i < 4; ++i)
#pragma unroll
            for (int j = 0; j < 4; ++j)
                acc[i][j] = __builtin_amdgcn_mfma_f32_16x16x32_bf16(
                    af[i], bf[j], acc[i][j], 0, 0, 0);
    }

    // epilogue (C/D: col = lane&15, row = (lane>>4)*4 + reg)
#pragma unroll
    for (int i = 0; i < 4; ++i) {
#pragma unroll
        for (int j = 0; j < 4; ++j) {
            const int col = n0 + wc + j * 16 + lrow;
            const float bv = bias[col];
            const int rbase = m0 + wr + i * 16 + kg * 4;
            if constexpr (OUT_MODE == 0) {
                float* Out = (float*)OutV;
#pragma unroll
                for (int r = 0; r < 4; ++r)
                    Out[(long)(rbase + r) * D_DIM + col] = acc[i][j][r] + bv;
            } else if constexpr (OUT_MODE == 1) {
                __hip_bfloat16* Out = (__hip_bfloat16*)OutV;
#pragma unroll
                for (int r = 0; r < 4; ++r)
                    Out[(long)(rbase + r) * D_DIM + col] =
                        __float2bfloat16(acc[i][j][r] + bv);
            } else {
                __hip_bfloat16* Out = (__hip_bfloat16*)OutV;
                const int hh = col >> 6, dd = col & 63;
                const int bb = rbase >> 10, s0 = rbase & 1023;
                __hip_bfloat16 o[4];
#pragma unroll
                for (int r = 0; r < 4; ++r)
                    o[r] = __float2bfloat16(acc[i][j][r] + bv);
                *(uint2*)&Out[((long)((bb * H_DIM + hh) * HD_DIM + dd)) * S_DIM + s0] =
                    *(uint2*)o;
            }
        }
    }
}

// ---------------------------------------------------------------------------
// RoPE: bf16 in -> bf16 out, table-driven. Q additionally scaled by 1/8.
// ---------------------------------------------------------------------------
__global__ __launch_bounds__(256) void rope_bf16_kernel(
    const __hip_bfloat16* __restrict__ Qi, const __hip_bfloat16* __restrict__ Ki,
    __hip_bfloat16* __restrict__ Qo, __hip_bfloat16* __restrict__ Ko,
    const float* __restrict__ tab)
{
    const long t = (long)blockIdx.x * 256 + threadIdx.x;  // 0..524287
    const int row = (int)(t >> 7);
    const int slot = (int)(t & 127);
    const int hh = slot >> 3;
    const int p0 = (slot & 7) * 4;
    const int pos = row & (S_DIM - 1);
    const bool isQ = (blockIdx.y == 0);
    const float scale = isQ ? 0.125f : 1.0f;

    const __hip_bfloat16* src = (isQ ? Qi : Ki) + (long)row * D_DIM + hh * HD_DIM;
    __hip_bfloat16* dst = (isQ ? Qo : Ko) + (long)row * D_DIM + hh * HD_DIM;

    short8 xv = *(const short8*)&src[2 * p0];
    float4 cv = *(const float4*)&tab[pos * 32 + p0];
    float4 sv = *(const float4*)&tab[32768 + pos * 32 + p0];
    float cc[4] = {cv.x, cv.y, cv.z, cv.w};
    float ss[4] = {sv.x, sv.y, sv.z, sv.w};

    __hip_bfloat16 o1[4], o2[4];
#pragma unroll
    for (int j = 0; j < 4; ++j) {
        float x1 = bf2f(xv[2 * j]);
        float x2 = bf2f(xv[2 * j + 1]);
        o1[j] = __float2bfloat16((x1 * cc[j] - x2 * ss[j]) * scale);
        o2[j] = __float2bfloat16((x1 * ss[j] + x2 * cc[j]) * scale);
    }
    *(uint2*)&dst[p0]      = *(uint2*)o1;
    *(uint2*)&dst[p0 + 32] = *(uint2*)o2;
}

// ---------------------------------------------------------------------------
// MFMA flash attention, swapped-QK^T softmax, prefetched staging, balanced qt.
// Block: 128 q-rows of one (b,h); 4 waves x 32 rows. Scale pre-folded into Q.
// ---------------------------------------------------------------------------
#define KPAD 72

__global__ __launch_bounds__(256, 2) void attn_mfma_kernel(
    const __hip_bfloat16* __restrict__ Q,
    const __hip_bfloat16* __restrict__ K,
    const __hip_bfloat16* __restrict__ Vt,
    __hip_bfloat16* __restrict__ CTX)
{
    __shared__ __align__(16) __hip_bfloat16 Kl[64][KPAD];
    __shared__ __align__(16) __hip_bfloat16 Vl[64][KPAD];
    __shared__ __align__(16) __hip_bfloat16 Pl[4][32][KPAD];
    __shared__ __align__(16) float aS[4][2][16];

    const int tid = threadIdx.x;
    const int l = tid & 63;
    const int w = tid >> 6;

    // balanced (b,h,qt) assignment: CU-paired blocks get qt and 7-qt
    const int bid = blockIdx.x + 8 * blockIdx.y + 128 * blockIdx.z;
    const int half = bid >> 8;
    const int idx = bid & 255;
    int qt = idx & 7;
    if (half) qt = 7 - qt;
    const int rest = idx >> 3;
    const int h = rest & 15;
    const int b = (rest >> 4) | (half << 1);

    const int lrow = l & 15;
    const int kg = l >> 4;
    const int kg4 = kg * 4;

    const int q0w = qt * 128 + w * 32;
    const long qrow_base = (long)b * S_DIM + q0w;

    // Q fragments in registers (B-operand layout == A layout per-lane)
    short8 qf[2][2];
#pragma unroll
    for (int m = 0; m < 2; ++m)
#pragma unroll
        for (int ks = 0; ks < 2; ++ks)
            qf[m][ks] = *(const short8*)&Q[(qrow_base + m * 16 + lrow) * D_DIM +
                                           h * HD_DIM + ks * 32 + kg * 8];

    f32x4 ctx[2][4];
#pragma unroll
    for (int m = 0; m < 2; ++m)
#pragma unroll
        for (int d = 0; d < 4; ++d) ctx[m][d] = (f32x4){0.f, 0.f, 0.f, 0.f};
    float mrun[2] = {-1e30f, -1e30f};
    float lrun[2] = {0.f, 0.f};

    // staging mapping: row tid>>2, 32B chunk (tid&3)
    const int sr = tid >> 2;
    const int sc2 = (tid & 3) * 16;
    const __hip_bfloat16* Kg = K + ((long)b * S_DIM + sr) * D_DIM + h * HD_DIM + sc2;
    const __hip_bfloat16* Vg = Vt + ((long)((b * H_DIM + h) * HD_DIM) + sr) * S_DIM + sc2;

    const int ktmax = 2 * qt + 1;

    // prologue: prefetch tile 0 into registers
    short8 kp0 = *(const short8*)Kg;
    short8 kp1 = *(const short8*)(Kg + 8);
    short8 vp0 = *(const short8*)Vg;
    short8 vp1 = *(const short8*)(Vg + 8);

    for (int kt = 0; kt <= ktmax; ++kt) {
        __syncthreads();                       // previous readers done
        *(short8*)&Kl[sr][sc2]     = kp0;
        *(short8*)&Kl[sr][sc2 + 8] = kp1;
        *(short8*)&Vl[sr][sc2]     = vp0;
        *(short8*)&Vl[sr][sc2 + 8] = vp1;
        if (kt < ktmax) {                      // prefetch next tile (in flight during compute)
            const __hip_bfloat16* kp = Kg + (long)(kt + 1) * 64 * D_DIM;
            const __hip_bfloat16* vp = Vg + (kt + 1) * 64;
            kp0 = *(const short8*)kp;
            kp1 = *(const short8*)(kp + 8);
            vp0 = *(const short8*)vp;
            vp1 = *(const short8*)(vp + 8);
        }
        __syncthreads();                       // LDS tile visible

        if (kt * 64 > q0w + 31) continue;      // fully masked for this wave

        // ---- S^T = K Q^T : lane holds q = q0w + m*16 + lrow, k = kt*64+nt*16+kg*4+r
        f32x4 sac[2][4];
#pragma unroll
        for (int m = 0; m < 2; ++m)
#pragma unroll
            for (int nt = 0; nt < 4; ++nt) sac[m][nt] = (f32x4){0.f, 0.f, 0.f, 0.f};

        short8 kf[4][2];
#pragma unroll
        for (int nt = 0; nt < 4; ++nt)
#pragma unroll
            for (int ks = 0; ks < 2; ++ks)
                kf[nt][ks] = *(const short8*)&Kl[nt * 16 + lrow][ks * 32 + kg * 8];
#pragma unroll
        for (int m = 0; m < 2; ++m)
#pragma unroll
            for (int nt = 0; nt < 4; ++nt)
#pragma unroll
                for (int ks = 0; ks < 2; ++ks)
                    sac[m][nt] = __builtin_amdgcn_mfma_f32_16x16x32_bf16(
                        kf[nt][ks], qf[m][ks], sac[m][nt], 0, 0, 0);

        // ---- online softmax, lane-local over 16 k-values + 2 shfl
        const bool partial = (kt * 64 + 63 > q0w);
        const int kbase = kt * 64;
#pragma unroll
        for (int m = 0; m < 2; ++m) {
            const int qg = q0w + m * 16 + lrow;
            float s[16];
#pragma unroll
            for (int nt = 0; nt < 4; ++nt)
#pragma unroll
                for (int r = 0; r < 4; ++r) {
                    float v = sac[m][nt][r];
                    if (partial && (kbase + nt * 16 + kg4 + r > qg)) v = -1e30f;
                    s[nt * 4 + r] = v;
                }
            float t8[8];
#pragma unroll
            for (int i = 0; i < 8; ++i) t8[i] = fmaxf(s[i], s[i + 8]);
#pragma unroll
            for (int i = 0; i < 4; ++i) t8[i] = fmaxf(t8[i], t8[i + 4]);
            float mx = fmaxf(fmaxf(t8[0], t8[1]), fmaxf(t8[2], t8[3]));
            mx = fmaxf(mx, __shfl_xor(mx, 16));
            mx = fmaxf(mx, __shfl_xor(mx, 32));
            const float mnew = fmaxf(mrun[m], mx);
            const float alpha = __expf(mrun[m] - mnew);
            mrun[m] = mnew;

            float p0s = 0.f, p1s = 0.f, p2s = 0.f, p3s = 0.f;
            __attribute__((aligned(8))) __hip_bfloat16 pb[16];
#pragma unroll
            for (int i = 0; i < 4; ++i) {
                float p = __expf(s[i] - mnew);      p0s += p; pb[i] = __float2bfloat16(p);
            }
#pragma unroll
            for (int i = 4; i < 8; ++i) {
                float p = __expf(s[i] - mnew);      p1s += p; pb[i] = __float2bfloat16(p);
            }
#pragma unroll
            for (int i = 8; i < 12; ++i) {
                float p = __expf(s[i] - mnew);      p2s += p; pb[i] = __float2bfloat16(p);
            }
#pragma unroll
            for (int i = 12; i < 16; ++i) {
                float p = __expf(s[i] - mnew);      p3s += p; pb[i] = __float2bfloat16(p);
            }
            float sum = (p0s + p1s) + (p2s + p3s);
            sum += __shfl_xor(sum, 16);
            sum += __shfl_xor(sum, 32);
            lrun[m] = lrun[m] * alpha + sum;

            if (kg == 0) aS[w][m][lrow] = alpha;
#pragma unroll
            for (int nt = 0; nt < 4; ++nt)
                *(uint2*)&Pl[w][m * 16 + lrow][nt * 16 + kg4] = *(uint2*)&pb[nt * 4];
        }

        // ---- rescale ctx by alpha (transposed via per-wave LDS, wave-sync)
#pragma unroll
        for (int m = 0; m < 2; ++m) {
            f32x4 al4 = *(const f32x4*)&aS[w][m][kg4];
#pragma unroll
            for (int dt = 0; dt < 4; ++dt)
#pragma unroll
                for (int r = 0; r < 4; ++r) ctx[m][dt][r] *= al4[r];
        }

        // ---- PV: ctx += P V  (A = P[q][k], B = V^T[d][k])
        short8 vf[4][2];
#pragma unroll
        for (int dt = 0; dt < 4; ++dt)
#pragma unroll
            for (int ks = 0; ks < 2; ++ks)
                vf[dt][ks] = *(const short8*)&Vl[dt * 16 + lrow][ks * 32 + kg * 8];
#pragma unroll
        for (int m = 0; m < 2; ++m) {
            short8 pf[2];
#pragma unroll
            for (int ks = 0; ks < 2; ++ks)
                pf[ks] = *(const short8*)&Pl[w][m * 16 + lrow][ks * 32 + kg * 8];
#pragma unroll
            for (int dt = 0; dt < 4; ++dt)
#pragma unroll
                for (int ks = 0; ks < 2; ++ks)
                    ctx[m][dt] = __builtin_amdgcn_mfma_f32_16x16x32_bf16(
                        pf[ks], vf[dt][ks], ctx[m][dt], 0, 0, 0);
        }
    }

    // ---- epilogue: transpose l via LDS, normalize, write bf16
    if (kg == 0) {
        aS[w][0][lrow] = lrun[0];
        aS[w][1][lrow] = lrun[1];
    }
#pragma unroll
    for (int m = 0; m < 2; ++m) {
        f32x4 lv = *(const f32x4*)&aS[w][m][kg4];
#pragma unroll
        for (int r = 0; r < 4; ++r) {
            const float inv_l = 1.0f / lv[r];
            const long rowoff = (qrow_base + m * 16 + kg4 + r) * D_DIM + h * HD_DIM;
#pragma unroll
            for (int dt = 0; dt < 4; ++dt)
                CTX[rowoff + dt * 16 + lrow] = __float2bfloat16(ctx[m][dt][r] * inv_l);
        }
    }
}

// ---------------------------------------------------------------------------
extern "C" void kernel_launch(void* const* d_in, const int* in_sizes, int n_in,
                              void* d_out, int out_size, void* d_ws, size_t ws_size,
                              hipStream_t stream)
{
    const float* query = (const float*)d_in[0];
    const float* key   = (const float*)d_in[1];
    const float* value = (const float*)d_in[2];
    const float* Wq = (const float*)d_in[4];
    const float* bq = (const float*)d_in[5];
    const float* Wk = (const float*)d_in[6];
    const float* bk = (const float*)d_in[7];
    const float* Wv = (const float*)d_in[8];
    const float* bv = (const float*)d_in[9];
    const float* Wo = (const float*)d_in[10];
    const float* bo = (const float*)d_in[11];

    char* wsb = (char*)d_ws;
    __hip_bfloat16* Qw    = (__hip_bfloat16*)(wsb);                 // 8 MB (pre-rope)
    __hip_bfloat16* Kw    = (__hip_bfloat16*)(wsb + (8L  << 20));   // 8 MB
    __hip_bfloat16* Vtb   = (__hip_bfloat16*)(wsb + (16L << 20));   // 8 MB
    __hip_bfloat16* Qbf   = (__hip_bfloat16*)(wsb + (24L << 20));   // 8 MB (roped)
    __hip_bfloat16* Kbf   = (__hip_bfloat16*)(wsb + (32L << 20));   // 8 MB
    __hip_bfloat16* CTXbf = (__hip_bfloat16*)(wsb + (40L << 20));   // 8 MB
    __hip_bfloat16* WtQ   = (__hip_bfloat16*)(wsb + (48L << 20));   // 2 MB
    __hip_bfloat16* WtK   = (__hip_bfloat16*)(wsb + (50L << 20));
    __hip_bfloat16* WtV   = (__hip_bfloat16*)(wsb + (52L << 20));
    __hip_bfloat16* WtO   = (__hip_bfloat16*)(wsb + (54L << 20));
    float*          tab   = (float*)(wsb + (56L << 20));            // 256 KB

    rope_table_kernel<<<128, 256, 0, stream>>>(tab);
    transpose4_to_bf16_kernel<<<dim3(32, 32, 4), 256, 0, stream>>>(
        Wq, Wk, Wv, Wo, WtQ, WtK, WtV, WtO);

    dim3 ggrid(D_DIM / 128, M_TOT / 128);   // (8, 32)
    gemm_mfma_t<1, true><<<ggrid, 256, 0, stream>>>(query, WtQ, bq, Qw);
    gemm_mfma_t<1, true><<<ggrid, 256, 0, stream>>>(key,   WtK, bk, Kw);
    gemm_mfma_t<2, true><<<ggrid, 256, 0, stream>>>(value, WtV, bv, Vtb);

    rope_bf16_kernel<<<dim3(2048, 2), 256, 0, stream>>>(Qw, Kw, Qbf, Kbf, tab);

    attn_mfma_kernel<<<dim3(8, 16, 4), 256, 0, stream>>>(Qbf, Kbf, Vtb, CTXbf);

    gemm_mfma_t<0, false><<<ggrid, 256, 0, stream>>>(CTXbf, WtO, bo, (float*)d_out);
}

// Round 5
// 138.649 us; speedup vs baseline: 6.7605x; 1.3671x over previous
//
#include <hip/hip_runtime.h>
#include <hip/hip_bf16.h>
#include <math.h>

#define B_DIM 4
#define S_DIM 1024
#define D_DIM 1024
#define H_DIM 16
#define HD_DIM 64
#define M_TOT 4096

typedef short short8 __attribute__((ext_vector_type(8)));
typedef float f32x4 __attribute__((ext_vector_type(4)));

__device__ inline float bf2f(short u)
{
    return __uint_as_float(((unsigned)(unsigned short)u) << 16);
}

__device__ inline void gload_lds16(const void* gsrc, void* lds)
{
    __builtin_amdgcn_global_load_lds(
        (const __attribute__((address_space(1))) unsigned int*)gsrc,
        (__attribute__((address_space(3))) unsigned int*)lds, 16, 0, 0);
}

// ---------------------------------------------------------------------------
// RoPE cos/sin table: tab[pos][i] = cos, tab[32768 + pos*32 + i] = sin
// ---------------------------------------------------------------------------
__global__ __launch_bounds__(256) void rope_table_kernel(float* __restrict__ tab)
{
    const int t = blockIdx.x * 256 + threadIdx.x;   // 0..32767
    const int pos = t >> 5, i = t & 31;
    float inv = powf(10000.0f, -(float)(2 * i) / 64.0f);
    float ang = (float)pos * inv;
    float s, c;
    sincosf(ang, &s, &c);
    tab[t] = c;
    tab[32768 + t] = s;
}

// ---------------------------------------------------------------------------
// Fused 4x transpose 1024x1024 fp32 W -> bf16 Wt (N,K layout)
// ---------------------------------------------------------------------------
__global__ __launch_bounds__(256) void transpose4_to_bf16_kernel(
    const float* __restrict__ W0, const float* __restrict__ W1,
    const float* __restrict__ W2, const float* __restrict__ W3,
    __hip_bfloat16* __restrict__ T0, __hip_bfloat16* __restrict__ T1,
    __hip_bfloat16* __restrict__ T2, __hip_bfloat16* __restrict__ T3)
{
    const float* W = (blockIdx.z == 0) ? W0 : (blockIdx.z == 1) ? W1
                    : (blockIdx.z == 2) ? W2 : W3;
    __hip_bfloat16* T = (blockIdx.z == 0) ? T0 : (blockIdx.z == 1) ? T1
                       : (blockIdx.z == 2) ? T2 : T3;

    __shared__ float tile[32][33];
    const int tid = threadIdx.x;
    const int r = tid >> 3;
    const int c4 = (tid & 7) * 4;

    float4 v = *(const float4*)&W[(long)(blockIdx.y * 32 + r) * D_DIM + blockIdx.x * 32 + c4];
    tile[r][c4 + 0] = v.x;
    tile[r][c4 + 1] = v.y;
    tile[r][c4 + 2] = v.z;
    tile[r][c4 + 3] = v.w;
    __syncthreads();

    __hip_bfloat16 o[4];
    o[0] = __float2bfloat16(tile[c4 + 0][r]);
    o[1] = __float2bfloat16(tile[c4 + 1][r]);
    o[2] = __float2bfloat16(tile[c4 + 2][r]);
    o[3] = __float2bfloat16(tile[c4 + 3][r]);
    *(uint2*)&T[(long)(blockIdx.x * 32 + r) * D_DIM + blockIdx.y * 32 + c4] = *(uint2*)o;
}

// ---------------------------------------------------------------------------
// Batched QKV GEMM: z in {0,1,2} selects (X, Wt, bias, output-mode).
// Out = X(M,K fp32) @ Wt(N,K bf16)^T + bias.
// A: fp32, register-prefetched (issued during MFMA phase) + cvt -> padded LDS.
// B: bf16 via global_load_lds (linear LDS).
// z<2 -> bf16 row-major out; z==2 -> bf16 V^T [b][h][d][s].
// ---------------------------------------------------------------------------
__global__ __launch_bounds__(256, 3) void gemm_qkv_kernel(
    const float* __restrict__ Xq, const float* __restrict__ Xk,
    const float* __restrict__ Xv,
    const __hip_bfloat16* __restrict__ WtQ, const __hip_bfloat16* __restrict__ WtK,
    const __hip_bfloat16* __restrict__ WtV,
    const float* __restrict__ bq, const float* __restrict__ bk,
    const float* __restrict__ bv,
    __hip_bfloat16* __restrict__ Qo, __hip_bfloat16* __restrict__ Ko,
    __hip_bfloat16* __restrict__ Vto)
{
    __shared__ __align__(16) __hip_bfloat16 Al[128][40];  // 80B rows (padded)
    __shared__ __align__(16) __hip_bfloat16 Bl[128][32];  // linear (gload_lds)

    const int z = blockIdx.z;
    const float* X = (z == 0) ? Xq : (z == 1) ? Xk : Xv;
    const __hip_bfloat16* Wt = (z == 0) ? WtQ : (z == 1) ? WtK : WtV;
    const float* bias = (z == 0) ? bq : (z == 1) ? bk : bv;

    const int tid = threadIdx.x;
    const int l = tid & 63;
    const int w = tid >> 6;
    const int m0 = blockIdx.y * 128;
    const int n0 = blockIdx.x * 128;

    // B staging (global_load_lds)
    const int srow = w * 16 + (l >> 2);
    const int skc = (l & 3) * 8;
    const __hip_bfloat16* Bbase = Wt + (long)(n0 + srow) * D_DIM + skc;
    char* ldsB0 = (char*)&Bl[0][0] + w * 1024;

    // A staging: row tid>>1, 16-float chunk (tid&1)*16
    const int arow = tid >> 1;
    const int ak = (tid & 1) * 16;
    const float* Af = X + (long)(m0 + arow) * D_DIM + ak;

    const int lrow = l & 15;
    const int kg = l >> 4;
    const int wr = (w >> 1) * 64;
    const int wc = (w & 1) * 64;

    f32x4 acc[4][4];
#pragma unroll
    for (int i = 0; i < 4; ++i)
#pragma unroll
        for (int j = 0; j < 4; ++j) acc[i][j] = (f32x4){0.f, 0.f, 0.f, 0.f};

    // prologue: fetch A chunk for k0 = 0
    float4 f0 = *(const float4*)(Af);
    float4 f1 = *(const float4*)(Af + 4);
    float4 f2 = *(const float4*)(Af + 8);
    float4 f3 = *(const float4*)(Af + 12);

    for (int k0 = 0; k0 < D_DIM; k0 += 32) {
        // convert the regs prefetched last iteration
        float fa[16] = {f0.x, f0.y, f0.z, f0.w, f1.x, f1.y, f1.z, f1.w,
                        f2.x, f2.y, f2.z, f2.w, f3.x, f3.y, f3.z, f3.w};
        __attribute__((aligned(16))) __hip_bfloat16 ab[16];
#pragma unroll
        for (int i = 0; i < 16; ++i) ab[i] = __float2bfloat16(fa[i]);

        __syncthreads();                       // previous-iter readers done
        *(short8*)&Al[arow][ak]     = ((const short8*)ab)[0];
        *(short8*)&Al[arow][ak + 8] = ((const short8*)ab)[1];
        gload_lds16(Bbase + k0, ldsB0);
        gload_lds16(Bbase + 64 * D_DIM + k0, ldsB0 + 4096);
        __syncthreads();                       // tile visible (vmcnt drain)

        // prefetch next A chunk -- stays in flight under the MFMA phase
        if (k0 + 32 < D_DIM) {
            f0 = *(const float4*)(Af + k0 + 32);
            f1 = *(const float4*)(Af + k0 + 36);
            f2 = *(const float4*)(Af + k0 + 40);
            f3 = *(const float4*)(Af + k0 + 44);
        }

        short8 af[4], bf[4];
#pragma unroll
        for (int i = 0; i < 4; ++i)
            af[i] = *(const short8*)&Al[wr + i * 16 + lrow][kg * 8];
#pragma unroll
        for (int j = 0; j < 4; ++j)
            bf[j] = *(const short8*)&Bl[wc + j * 16 + lrow][kg * 8];
#pragma unroll
        for (int i = 0; i < 4; ++i)
#pragma unroll
            for (int j = 0; j < 4; ++j)
                acc[i][j] = __builtin_amdgcn_mfma_f32_16x16x32_bf16(
                    af[i], bf[j], acc[i][j], 0, 0, 0);
    }

    // epilogue (C/D: col = lane&15, row = (lane>>4)*4 + reg)
#pragma unroll
    for (int i = 0; i < 4; ++i) {
#pragma unroll
        for (int j = 0; j < 4; ++j) {
            const int col = n0 + wc + j * 16 + lrow;
            const float bvs = bias[col];
            const int rbase = m0 + wr + i * 16 + kg * 4;
            if (z < 2) {
                __hip_bfloat16* Out = (z == 0) ? Qo : Ko;
#pragma unroll
                for (int r = 0; r < 4; ++r)
                    Out[(long)(rbase + r) * D_DIM + col] =
                        __float2bfloat16(acc[i][j][r] + bvs);
            } else {
                const int hh = col >> 6, dd = col & 63;
                const int bb = rbase >> 10, s0 = rbase & 1023;
                __hip_bfloat16 o[4];
#pragma unroll
                for (int r = 0; r < 4; ++r)
                    o[r] = __float2bfloat16(acc[i][j][r] + bvs);
                *(uint2*)&Vto[((long)((bb * H_DIM + hh) * HD_DIM + dd)) * S_DIM + s0] =
                    *(uint2*)o;
            }
        }
    }
}

// ---------------------------------------------------------------------------
// Final projection GEMM: Out(M,N fp32) = X(M,K bf16) @ Wt(N,K bf16)^T + bias
// ---------------------------------------------------------------------------
__global__ __launch_bounds__(256) void gemm_wo_kernel(
    const __hip_bfloat16* __restrict__ X, const __hip_bfloat16* __restrict__ Wt,
    const float* __restrict__ bias, float* __restrict__ Out)
{
    __shared__ __align__(16) __hip_bfloat16 Al[128][32];
    __shared__ __align__(16) __hip_bfloat16 Bl[128][32];

    const int tid = threadIdx.x;
    const int l = tid & 63;
    const int w = tid >> 6;
    const int m0 = blockIdx.y * 128;
    const int n0 = blockIdx.x * 128;

    const int srow = w * 16 + (l >> 2);
    const int skc = (l & 3) * 8;
    const __hip_bfloat16* Abase = X + (long)(m0 + srow) * D_DIM + skc;
    const __hip_bfloat16* Bbase = Wt + (long)(n0 + srow) * D_DIM + skc;
    char* ldsA0 = (char*)&Al[0][0] + w * 1024;
    char* ldsB0 = (char*)&Bl[0][0] + w * 1024;

    const int lrow = l & 15;
    const int kg = l >> 4;
    const int wr = (w >> 1) * 64;
    const int wc = (w & 1) * 64;

    f32x4 acc[4][4];
#pragma unroll
    for (int i = 0; i < 4; ++i)
#pragma unroll
        for (int j = 0; j < 4; ++j) acc[i][j] = (f32x4){0.f, 0.f, 0.f, 0.f};

    for (int k0 = 0; k0 < D_DIM; k0 += 32) {
        __syncthreads();
        gload_lds16(Abase + k0, ldsA0);
        gload_lds16(Abase + 64 * D_DIM + k0, ldsA0 + 4096);
        gload_lds16(Bbase + k0, ldsB0);
        gload_lds16(Bbase + 64 * D_DIM + k0, ldsB0 + 4096);
        __syncthreads();

        short8 af[4], bf[4];
#pragma unroll
        for (int i = 0; i < 4; ++i)
            af[i] = *(const short8*)&Al[wr + i * 16 + lrow][kg * 8];
#pragma unroll
        for (int j = 0; j < 4; ++j)
            bf[j] = *(const short8*)&Bl[wc + j * 16 + lrow][kg * 8];
#pragma unroll
        for (int i = 0; i < 4; ++i)
#pragma unroll
            for (int j = 0; j < 4; ++j)
                acc[i][j] = __builtin_amdgcn_mfma_f32_16x16x32_bf16(
                    af[i], bf[j], acc[i][j], 0, 0, 0);
    }

#pragma unroll
    for (int i = 0; i < 4; ++i) {
#pragma unroll
        for (int j = 0; j < 4; ++j) {
            const int col = n0 + wc + j * 16 + lrow;
            const float bv = bias[col];
            const int rbase = m0 + wr + i * 16 + kg * 4;
#pragma unroll
            for (int r = 0; r < 4; ++r)
                Out[(long)(rbase + r) * D_DIM + col] = acc[i][j][r] + bv;
        }
    }
}

// ---------------------------------------------------------------------------
// RoPE: bf16 in -> bf16 out, table-driven. Q additionally scaled by 1/8.
// ---------------------------------------------------------------------------
__global__ __launch_bounds__(256) void rope_bf16_kernel(
    const __hip_bfloat16* __restrict__ Qi, const __hip_bfloat16* __restrict__ Ki,
    __hip_bfloat16* __restrict__ Qo, __hip_bfloat16* __restrict__ Ko,
    const float* __restrict__ tab)
{
    const long t = (long)blockIdx.x * 256 + threadIdx.x;  // 0..524287
    const int row = (int)(t >> 7);
    const int slot = (int)(t & 127);
    const int hh = slot >> 3;
    const int p0 = (slot & 7) * 4;
    const int pos = row & (S_DIM - 1);
    const bool isQ = (blockIdx.y == 0);
    const float scale = isQ ? 0.125f : 1.0f;

    const __hip_bfloat16* src = (isQ ? Qi : Ki) + (long)row * D_DIM + hh * HD_DIM;
    __hip_bfloat16* dst = (isQ ? Qo : Ko) + (long)row * D_DIM + hh * HD_DIM;

    short8 xv = *(const short8*)&src[2 * p0];
    float4 cv = *(const float4*)&tab[pos * 32 + p0];
    float4 sv = *(const float4*)&tab[32768 + pos * 32 + p0];
    float cc[4] = {cv.x, cv.y, cv.z, cv.w};
    float ss[4] = {sv.x, sv.y, sv.z, sv.w};

    __hip_bfloat16 o1[4], o2[4];
#pragma unroll
    for (int j = 0; j < 4; ++j) {
        float x1 = bf2f(xv[2 * j]);
        float x2 = bf2f(xv[2 * j + 1]);
        o1[j] = __float2bfloat16((x1 * cc[j] - x2 * ss[j]) * scale);
        o2[j] = __float2bfloat16((x1 * ss[j] + x2 * cc[j]) * scale);
    }
    *(uint2*)&dst[p0]      = *(uint2*)o1;
    *(uint2*)&dst[p0 + 32] = *(uint2*)o2;
}

// ---------------------------------------------------------------------------
// MFMA flash attention, swapped-QK^T softmax, prefetched staging, balanced qt.
// ---------------------------------------------------------------------------
#define KPAD 72

__global__ __launch_bounds__(256, 2) void attn_mfma_kernel(
    const __hip_bfloat16* __restrict__ Q,
    const __hip_bfloat16* __restrict__ K,
    const __hip_bfloat16* __restrict__ Vt,
    __hip_bfloat16* __restrict__ CTX)
{
    __shared__ __align__(16) __hip_bfloat16 Kl[64][KPAD];
    __shared__ __align__(16) __hip_bfloat16 Vl[64][KPAD];
    __shared__ __align__(16) __hip_bfloat16 Pl[4][32][KPAD];
    __shared__ __align__(16) float aS[4][2][16];

    const int tid = threadIdx.x;
    const int l = tid & 63;
    const int w = tid >> 6;

    const int bid = blockIdx.x + 8 * blockIdx.y + 128 * blockIdx.z;
    const int half = bid >> 8;
    const int idx = bid & 255;
    int qt = idx & 7;
    if (half) qt = 7 - qt;
    const int rest = idx >> 3;
    const int h = rest & 15;
    const int b = (rest >> 4) | (half << 1);

    const int lrow = l & 15;
    const int kg = l >> 4;
    const int kg4 = kg * 4;

    const int q0w = qt * 128 + w * 32;
    const long qrow_base = (long)b * S_DIM + q0w;

    short8 qf[2][2];
#pragma unroll
    for (int m = 0; m < 2; ++m)
#pragma unroll
        for (int ks = 0; ks < 2; ++ks)
            qf[m][ks] = *(const short8*)&Q[(qrow_base + m * 16 + lrow) * D_DIM +
                                           h * HD_DIM + ks * 32 + kg * 8];

    f32x4 ctx[2][4];
#pragma unroll
    for (int m = 0; m < 2; ++m)
#pragma unroll
        for (int d = 0; d < 4; ++d) ctx[m][d] = (f32x4){0.f, 0.f, 0.f, 0.f};
    float mrun[2] = {-1e30f, -1e30f};
    float lrun[2] = {0.f, 0.f};

    const int sr = tid >> 2;
    const int sc2 = (tid & 3) * 16;
    const __hip_bfloat16* Kg = K + ((long)b * S_DIM + sr) * D_DIM + h * HD_DIM + sc2;
    const __hip_bfloat16* Vg = Vt + ((long)((b * H_DIM + h) * HD_DIM) + sr) * S_DIM + sc2;

    const int ktmax = 2 * qt + 1;

    short8 kp0 = *(const short8*)Kg;
    short8 kp1 = *(const short8*)(Kg + 8);
    short8 vp0 = *(const short8*)Vg;
    short8 vp1 = *(const short8*)(Vg + 8);

    for (int kt = 0; kt <= ktmax; ++kt) {
        __syncthreads();
        *(short8*)&Kl[sr][sc2]     = kp0;
        *(short8*)&Kl[sr][sc2 + 8] = kp1;
        *(short8*)&Vl[sr][sc2]     = vp0;
        *(short8*)&Vl[sr][sc2 + 8] = vp1;
        if (kt < ktmax) {
            const __hip_bfloat16* kp = Kg + (long)(kt + 1) * 64 * D_DIM;
            const __hip_bfloat16* vp = Vg + (kt + 1) * 64;
            kp0 = *(const short8*)kp;
            kp1 = *(const short8*)(kp + 8);
            vp0 = *(const short8*)vp;
            vp1 = *(const short8*)(vp + 8);
        }
        __syncthreads();

        if (kt * 64 > q0w + 31) continue;

        f32x4 sac[2][4];
#pragma unroll
        for (int m = 0; m < 2; ++m)
#pragma unroll
            for (int nt = 0; nt < 4; ++nt) sac[m][nt] = (f32x4){0.f, 0.f, 0.f, 0.f};

        short8 kf[4][2];
#pragma unroll
        for (int nt = 0; nt < 4; ++nt)
#pragma unroll
            for (int ks = 0; ks < 2; ++ks)
                kf[nt][ks] = *(const short8*)&Kl[nt * 16 + lrow][ks * 32 + kg * 8];
#pragma unroll
        for (int m = 0; m < 2; ++m)
#pragma unroll
            for (int nt = 0; nt < 4; ++nt)
#pragma unroll
                for (int ks = 0; ks < 2; ++ks)
                    sac[m][nt] = __builtin_amdgcn_mfma_f32_16x16x32_bf16(
                        kf[nt][ks], qf[m][ks], sac[m][nt], 0, 0, 0);

        const bool partial = (kt * 64 + 63 > q0w);
        const int kbase = kt * 64;
#pragma unroll
        for (int m = 0; m < 2; ++m) {
            const int qg = q0w + m * 16 + lrow;
            float s[16];
#pragma unroll
            for (int nt = 0; nt < 4; ++nt)
#pragma unroll
                for (int r = 0; r < 4; ++r) {
                    float v = sac[m][nt][r];
                    if (partial && (kbase + nt * 16 + kg4 + r > qg)) v = -1e30f;
                    s[nt * 4 + r] = v;
                }
            float t8[8];
#pragma unroll
            for (int i = 0; i < 8; ++i) t8[i] = fmaxf(s[i], s[i + 8]);
#pragma unroll
            for (int i = 0; i < 4; ++i) t8[i] = fmaxf(t8[i], t8[i + 4]);
            float mx = fmaxf(fmaxf(t8[0], t8[1]), fmaxf(t8[2], t8[3]));
            mx = fmaxf(mx, __shfl_xor(mx, 16));
            mx = fmaxf(mx, __shfl_xor(mx, 32));
            const float mnew = fmaxf(mrun[m], mx);
            const float alpha = __expf(mrun[m] - mnew);
            mrun[m] = mnew;

            float p0s = 0.f, p1s = 0.f, p2s = 0.f, p3s = 0.f;
            __attribute__((aligned(8))) __hip_bfloat16 pb[16];
#pragma unroll
            for (int i = 0; i < 4; ++i) {
                float p = __expf(s[i] - mnew);      p0s += p; pb[i] = __float2bfloat16(p);
            }
#pragma unroll
            for (int i = 4; i < 8; ++i) {
                float p = __expf(s[i] - mnew);      p1s += p; pb[i] = __float2bfloat16(p);
            }
#pragma unroll
            for (int i = 8; i < 12; ++i) {
                float p = __expf(s[i] - mnew);      p2s += p; pb[i] = __float2bfloat16(p);
            }
#pragma unroll
            for (int i = 12; i < 16; ++i) {
                float p = __expf(s[i] - mnew);      p3s += p; pb[i] = __float2bfloat16(p);
            }
            float sum = (p0s + p1s) + (p2s + p3s);
            sum += __shfl_xor(sum, 16);
            sum += __shfl_xor(sum, 32);
            lrun[m] = lrun[m] * alpha + sum;

            if (kg == 0) aS[w][m][lrow] = alpha;
#pragma unroll
            for (int nt = 0; nt < 4; ++nt)
                *(uint2*)&Pl[w][m * 16 + lrow][nt * 16 + kg4] = *(uint2*)&pb[nt * 4];
        }

#pragma unroll
        for (int m = 0; m < 2; ++m) {
            f32x4 al4 = *(const f32x4*)&aS[w][m][kg4];
#pragma unroll
            for (int dt = 0; dt < 4; ++dt)
#pragma unroll
                for (int r = 0; r < 4; ++r) ctx[m][dt][r] *= al4[r];
        }

        short8 vf[4][2];
#pragma unroll
        for (int dt = 0; dt < 4; ++dt)
#pragma unroll
            for (int ks = 0; ks < 2; ++ks)
                vf[dt][ks] = *(const short8*)&Vl[dt * 16 + lrow][ks * 32 + kg * 8];
#pragma unroll
        for (int m = 0; m < 2; ++m) {
            short8 pf[2];
#pragma unroll
            for (int ks = 0; ks < 2; ++ks)
                pf[ks] = *(const short8*)&Pl[w][m * 16 + lrow][ks * 32 + kg * 8];
#pragma unroll
            for (int dt = 0; dt < 4; ++dt)
#pragma unroll
                for (int ks = 0; ks < 2; ++ks)
                    ctx[m][dt] = __builtin_amdgcn_mfma_f32_16x16x32_bf16(
                        pf[ks], vf[dt][ks], ctx[m][dt], 0, 0, 0);
        }
    }

    if (kg == 0) {
        aS[w][0][lrow] = lrun[0];
        aS[w][1][lrow] = lrun[1];
    }
#pragma unroll
    for (int m = 0; m < 2; ++m) {
        f32x4 lv = *(const f32x4*)&aS[w][m][kg4];
#pragma unroll
        for (int r = 0; r < 4; ++r) {
            const float inv_l = 1.0f / lv[r];
            const long rowoff = (qrow_base + m * 16 + kg4 + r) * D_DIM + h * HD_DIM;
#pragma unroll
            for (int dt = 0; dt < 4; ++dt)
                CTX[rowoff + dt * 16 + lrow] = __float2bfloat16(ctx[m][dt][r] * inv_l);
        }
    }
}

// ---------------------------------------------------------------------------
extern "C" void kernel_launch(void* const* d_in, const int* in_sizes, int n_in,
                              void* d_out, int out_size, void* d_ws, size_t ws_size,
                              hipStream_t stream)
{
    const float* query = (const float*)d_in[0];
    const float* key   = (const float*)d_in[1];
    const float* value = (const float*)d_in[2];
    const float* Wq = (const float*)d_in[4];
    const float* bq = (const float*)d_in[5];
    const float* Wk = (const float*)d_in[6];
    const float* bk = (const float*)d_in[7];
    const float* Wv = (const float*)d_in[8];
    const float* bv = (const float*)d_in[9];
    const float* Wo = (const float*)d_in[10];
    const float* bo = (const float*)d_in[11];

    char* wsb = (char*)d_ws;
    __hip_bfloat16* Qw    = (__hip_bfloat16*)(wsb);                 // 8 MB (pre-rope)
    __hip_bfloat16* Kw    = (__hip_bfloat16*)(wsb + (8L  << 20));   // 8 MB
    __hip_bfloat16* Vtb   = (__hip_bfloat16*)(wsb + (16L << 20));   // 8 MB
    __hip_bfloat16* Qbf   = (__hip_bfloat16*)(wsb + (24L << 20));   // 8 MB (roped)
    __hip_bfloat16* Kbf   = (__hip_bfloat16*)(wsb + (32L << 20));   // 8 MB
    __hip_bfloat16* CTXbf = (__hip_bfloat16*)(wsb + (40L << 20));   // 8 MB
    __hip_bfloat16* WtQ   = (__hip_bfloat16*)(wsb + (48L << 20));   // 2 MB
    __hip_bfloat16* WtK   = (__hip_bfloat16*)(wsb + (50L << 20));
    __hip_bfloat16* WtV   = (__hip_bfloat16*)(wsb + (52L << 20));
    __hip_bfloat16* WtO   = (__hip_bfloat16*)(wsb + (54L << 20));
    float*          tab   = (float*)(wsb + (56L << 20));            // 256 KB

    rope_table_kernel<<<128, 256, 0, stream>>>(tab);
    transpose4_to_bf16_kernel<<<dim3(32, 32, 4), 256, 0, stream>>>(
        Wq, Wk, Wv, Wo, WtQ, WtK, WtV, WtO);

    gemm_qkv_kernel<<<dim3(8, 32, 3), 256, 0, stream>>>(
        query, key, value, WtQ, WtK, WtV, bq, bk, bv, Qw, Kw, Vtb);

    rope_bf16_kernel<<<dim3(2048, 2), 256, 0, stream>>>(Qw, Kw, Qbf, Kbf, tab);

    attn_mfma_kernel<<<dim3(8, 16, 4), 256, 0, stream>>>(Qbf, Kbf, Vtb, CTXbf);

    gemm_wo_kernel<<<dim3(8, 32), 256, 0, stream>>>(CTXbf, WtO, bo, (float*)d_out);
}

// Round 6
// 116.463 us; speedup vs baseline: 8.0483x; 1.1905x over previous
//
#include <hip/hip_runtime.h>
#include <hip/hip_bf16.h>
#include <math.h>

#define B_DIM 4
#define S_DIM 1024
#define D_DIM 1024
#define H_DIM 16
#define HD_DIM 64
#define M_TOT 4096

typedef short short8 __attribute__((ext_vector_type(8)));
typedef float f32x4 __attribute__((ext_vector_type(4)));

__device__ inline float bf2f(short u)
{
    return __uint_as_float(((unsigned)(unsigned short)u) << 16);
}

__device__ inline void gload_lds16(const void* gsrc, void* lds)
{
    __builtin_amdgcn_global_load_lds(
        (const __attribute__((address_space(1))) unsigned int*)gsrc,
        (__attribute__((address_space(3))) unsigned int*)lds, 16, 0, 0);
}

// ---------------------------------------------------------------------------
// RoPE cos/sin table
// ---------------------------------------------------------------------------
__global__ __launch_bounds__(256) void rope_table_kernel(float* __restrict__ tab)
{
    const int t = blockIdx.x * 256 + threadIdx.x;   // 0..32767
    const int pos = t >> 5, i = t & 31;
    float inv = powf(10000.0f, -(float)(2 * i) / 64.0f);
    float ang = (float)pos * inv;
    float s, c;
    sincosf(ang, &s, &c);
    tab[t] = c;
    tab[32768 + t] = s;
}

// ---------------------------------------------------------------------------
// Fused 4x transpose 1024x1024 fp32 W -> bf16 Wt (N,K layout)
// ---------------------------------------------------------------------------
__global__ __launch_bounds__(256) void transpose4_to_bf16_kernel(
    const float* __restrict__ W0, const float* __restrict__ W1,
    const float* __restrict__ W2, const float* __restrict__ W3,
    __hip_bfloat16* __restrict__ T0, __hip_bfloat16* __restrict__ T1,
    __hip_bfloat16* __restrict__ T2, __hip_bfloat16* __restrict__ T3)
{
    const float* W = (blockIdx.z == 0) ? W0 : (blockIdx.z == 1) ? W1
                    : (blockIdx.z == 2) ? W2 : W3;
    __hip_bfloat16* T = (blockIdx.z == 0) ? T0 : (blockIdx.z == 1) ? T1
                       : (blockIdx.z == 2) ? T2 : T3;

    __shared__ float tile[32][33];
    const int tid = threadIdx.x;
    const int r = tid >> 3;
    const int c4 = (tid & 7) * 4;

    float4 v = *(const float4*)&W[(long)(blockIdx.y * 32 + r) * D_DIM + blockIdx.x * 32 + c4];
    tile[r][c4 + 0] = v.x;
    tile[r][c4 + 1] = v.y;
    tile[r][c4 + 2] = v.z;
    tile[r][c4 + 3] = v.w;
    __syncthreads();

    __hip_bfloat16 o[4];
    o[0] = __float2bfloat16(tile[c4 + 0][r]);
    o[1] = __float2bfloat16(tile[c4 + 1][r]);
    o[2] = __float2bfloat16(tile[c4 + 2][r]);
    o[3] = __float2bfloat16(tile[c4 + 3][r]);
    *(uint2*)&T[(long)(blockIdx.x * 32 + r) * D_DIM + blockIdx.y * 32 + c4] = *(uint2*)o;
}

// ---------------------------------------------------------------------------
// Batched QKV GEMM with XCD-panel-grouped swizzle.
// Work remap: F = flat block id; xcd = F&7; within an XCD: n fastest, then
// 4 m-panels, then z. All 8 n-blocks of one (m,z) A-panel share the XCD,
// so the fp32 A panel is fetched from HBM once and served from that L2.
// ---------------------------------------------------------------------------
__global__ __launch_bounds__(256, 3) void gemm_qkv_kernel(
    const float* __restrict__ Xq, const float* __restrict__ Xk,
    const float* __restrict__ Xv,
    const __hip_bfloat16* __restrict__ WtQ, const __hip_bfloat16* __restrict__ WtK,
    const __hip_bfloat16* __restrict__ WtV,
    const float* __restrict__ bq, const float* __restrict__ bk,
    const float* __restrict__ bv,
    __hip_bfloat16* __restrict__ Qo, __hip_bfloat16* __restrict__ Ko,
    __hip_bfloat16* __restrict__ Vto)
{
    __shared__ __align__(16) __hip_bfloat16 Al[128][40];  // padded (reg-staged A)
    __shared__ __align__(16) __hip_bfloat16 Bl[128][32];  // linear (gload_lds)

    // ---- XCD-grouped work assignment (bijective on [0,768)) ----
    const int F = blockIdx.x + 8 * blockIdx.y + 256 * blockIdx.z;
    const int xcd = F & 7;
    const int s = F >> 3;                 // 0..95
    const int z = s >> 5;                 // 0..2
    const int n0 = (s & 7) * 128;
    const int m0 = ((xcd << 2) | ((s >> 3) & 3)) * 128;

    const float* X = (z == 0) ? Xq : (z == 1) ? Xk : Xv;
    const __hip_bfloat16* Wt = (z == 0) ? WtQ : (z == 1) ? WtK : WtV;
    const float* bias = (z == 0) ? bq : (z == 1) ? bk : bv;

    const int tid = threadIdx.x;
    const int l = tid & 63;
    const int w = tid >> 6;

    // B staging (global_load_lds)
    const int srow = w * 16 + (l >> 2);
    const int skc = (l & 3) * 8;
    const __hip_bfloat16* Bbase = Wt + (long)(n0 + srow) * D_DIM + skc;
    char* ldsB0 = (char*)&Bl[0][0] + w * 1024;

    // A staging: row tid>>1, 16-float chunk (tid&1)*16
    const int arow = tid >> 1;
    const int ak = (tid & 1) * 16;
    const float* Af = X + (long)(m0 + arow) * D_DIM + ak;

    const int lrow = l & 15;
    const int kg = l >> 4;
    const int wr = (w >> 1) * 64;
    const int wc = (w & 1) * 64;

    f32x4 acc[4][4];
#pragma unroll
    for (int i = 0; i < 4; ++i)
#pragma unroll
        for (int j = 0; j < 4; ++j) acc[i][j] = (f32x4){0.f, 0.f, 0.f, 0.f};

    float4 f0 = *(const float4*)(Af);
    float4 f1 = *(const float4*)(Af + 4);
    float4 f2 = *(const float4*)(Af + 8);
    float4 f3 = *(const float4*)(Af + 12);

    for (int k0 = 0; k0 < D_DIM; k0 += 32) {
        float fa[16] = {f0.x, f0.y, f0.z, f0.w, f1.x, f1.y, f1.z, f1.w,
                        f2.x, f2.y, f2.z, f2.w, f3.x, f3.y, f3.z, f3.w};
        __attribute__((aligned(16))) __hip_bfloat16 ab[16];
#pragma unroll
        for (int i = 0; i < 16; ++i) ab[i] = __float2bfloat16(fa[i]);

        __syncthreads();
        *(short8*)&Al[arow][ak]     = ((const short8*)ab)[0];
        *(short8*)&Al[arow][ak + 8] = ((const short8*)ab)[1];
        gload_lds16(Bbase + k0, ldsB0);
        gload_lds16(Bbase + 64 * D_DIM + k0, ldsB0 + 4096);
        __syncthreads();

        if (k0 + 32 < D_DIM) {
            f0 = *(const float4*)(Af + k0 + 32);
            f1 = *(const float4*)(Af + k0 + 36);
            f2 = *(const float4*)(Af + k0 + 40);
            f3 = *(const float4*)(Af + k0 + 44);
        }

        short8 af[4], bf[4];
#pragma unroll
        for (int i = 0; i < 4; ++i)
            af[i] = *(const short8*)&Al[wr + i * 16 + lrow][kg * 8];
#pragma unroll
        for (int j = 0; j < 4; ++j)
            bf[j] = *(const short8*)&Bl[wc + j * 16 + lrow][kg * 8];
#pragma unroll
        for (int i = 0; i < 4; ++i)
#pragma unroll
            for (int j = 0; j < 4; ++j)
                acc[i][j] = __builtin_amdgcn_mfma_f32_16x16x32_bf16(
                    af[i], bf[j], acc[i][j], 0, 0, 0);
    }

#pragma unroll
    for (int i = 0; i < 4; ++i) {
#pragma unroll
        for (int j = 0; j < 4; ++j) {
            const int col = n0 + wc + j * 16 + lrow;
            const float bvs = bias[col];
            const int rbase = m0 + wr + i * 16 + kg * 4;
            if (z < 2) {
                __hip_bfloat16* Out = (z == 0) ? Qo : Ko;
#pragma unroll
                for (int r = 0; r < 4; ++r)
                    Out[(long)(rbase + r) * D_DIM + col] =
                        __float2bfloat16(acc[i][j][r] + bvs);
            } else {
                const int hh = col >> 6, dd = col & 63;
                const int bb = rbase >> 10, s0 = rbase & 1023;
                __hip_bfloat16 o[4];
#pragma unroll
                for (int r = 0; r < 4; ++r)
                    o[r] = __float2bfloat16(acc[i][j][r] + bvs);
                *(uint2*)&Vto[((long)((bb * H_DIM + hh) * HD_DIM + dd)) * S_DIM + s0] =
                    *(uint2*)o;
            }
        }
    }
}

// ---------------------------------------------------------------------------
// Final projection: Out(M,N fp32) = X(M,K bf16) @ Wt(N,K bf16)^T + bias
// 128x64 tile -> 512 blocks (2/CU) + XCD swizzle. Wave = 64x32 out (acc 4x2).
// ---------------------------------------------------------------------------
__global__ __launch_bounds__(256, 2) void gemm_wo_kernel(
    const __hip_bfloat16* __restrict__ X, const __hip_bfloat16* __restrict__ Wt,
    const float* __restrict__ bias, float* __restrict__ Out)
{
    __shared__ __align__(16) __hip_bfloat16 Al[128][32];  // 8 KB
    __shared__ __align__(16) __hip_bfloat16 Bl[64][32];   // 4 KB

    // XCD-grouped remap (bijective on [0,512)): per XCD 4 m-panels x 16 n
    const int F = blockIdx.x;
    const int xcd = F & 7;
    const int s = F >> 3;                 // 0..63
    const int n0 = (s & 15) * 64;
    const int m0 = ((xcd << 2) | (s >> 4)) * 128;

    const int tid = threadIdx.x;
    const int l = tid & 63;
    const int w = tid >> 6;

    const int srow = w * 16 + (l >> 2);
    const int skc = (l & 3) * 8;
    const __hip_bfloat16* Abase = X + (long)(m0 + srow) * D_DIM + skc;
    const __hip_bfloat16* Bbase = Wt + (long)(n0 + srow) * D_DIM + skc;
    char* ldsA0 = (char*)&Al[0][0] + w * 1024;
    char* ldsB0 = (char*)&Bl[0][0] + w * 1024;

    const int lrow = l & 15;
    const int kg = l >> 4;
    const int wr = (w >> 1) * 64;   // wave row: 0 / 64
    const int wc = (w & 1) * 32;    // wave col: 0 / 32

    f32x4 acc[4][2];
#pragma unroll
    for (int i = 0; i < 4; ++i)
#pragma unroll
        for (int j = 0; j < 2; ++j) acc[i][j] = (f32x4){0.f, 0.f, 0.f, 0.f};

    for (int k0 = 0; k0 < D_DIM; k0 += 32) {
        __syncthreads();
        gload_lds16(Abase + k0, ldsA0);
        gload_lds16(Abase + 64 * D_DIM + k0, ldsA0 + 4096);
        gload_lds16(Bbase + k0, ldsB0);
        __syncthreads();

        short8 af[4], bf[2];
#pragma unroll
        for (int i = 0; i < 4; ++i)
            af[i] = *(const short8*)&Al[wr + i * 16 + lrow][kg * 8];
#pragma unroll
        for (int j = 0; j < 2; ++j)
            bf[j] = *(const short8*)&Bl[wc + j * 16 + lrow][kg * 8];
#pragma unroll
        for (int i = 0; i < 4; ++i)
#pragma unroll
            for (int j = 0; j < 2; ++j)
                acc[i][j] = __builtin_amdgcn_mfma_f32_16x16x32_bf16(
                    af[i], bf[j], acc[i][j], 0, 0, 0);
    }

#pragma unroll
    for (int i = 0; i < 4; ++i) {
#pragma unroll
        for (int j = 0; j < 2; ++j) {
            const int col = n0 + wc + j * 16 + lrow;
            const float bv = bias[col];
            const int rbase = m0 + wr + i * 16 + kg * 4;
#pragma unroll
            for (int r = 0; r < 4; ++r)
                Out[(long)(rbase + r) * D_DIM + col] = acc[i][j][r] + bv;
        }
    }
}

// ---------------------------------------------------------------------------
// RoPE: bf16 in -> bf16 out, table-driven. Q additionally scaled by 1/8.
// ---------------------------------------------------------------------------
__global__ __launch_bounds__(256) void rope_bf16_kernel(
    const __hip_bfloat16* __restrict__ Qi, const __hip_bfloat16* __restrict__ Ki,
    __hip_bfloat16* __restrict__ Qo, __hip_bfloat16* __restrict__ Ko,
    const float* __restrict__ tab)
{
    const long t = (long)blockIdx.x * 256 + threadIdx.x;  // 0..524287
    const int row = (int)(t >> 7);
    const int slot = (int)(t & 127);
    const int hh = slot >> 3;
    const int p0 = (slot & 7) * 4;
    const int pos = row & (S_DIM - 1);
    const bool isQ = (blockIdx.y == 0);
    const float scale = isQ ? 0.125f : 1.0f;

    const __hip_bfloat16* src = (isQ ? Qi : Ki) + (long)row * D_DIM + hh * HD_DIM;
    __hip_bfloat16* dst = (isQ ? Qo : Ko) + (long)row * D_DIM + hh * HD_DIM;

    short8 xv = *(const short8*)&src[2 * p0];
    float4 cv = *(const float4*)&tab[pos * 32 + p0];
    float4 sv = *(const float4*)&tab[32768 + pos * 32 + p0];
    float cc[4] = {cv.x, cv.y, cv.z, cv.w};
    float ss[4] = {sv.x, sv.y, sv.z, sv.w};

    __hip_bfloat16 o1[4], o2[4];
#pragma unroll
    for (int j = 0; j < 4; ++j) {
        float x1 = bf2f(xv[2 * j]);
        float x2 = bf2f(xv[2 * j + 1]);
        o1[j] = __float2bfloat16((x1 * cc[j] - x2 * ss[j]) * scale);
        o2[j] = __float2bfloat16((x1 * ss[j] + x2 * cc[j]) * scale);
    }
    *(uint2*)&dst[p0]      = *(uint2*)o1;
    *(uint2*)&dst[p0 + 32] = *(uint2*)o2;
}

// ---------------------------------------------------------------------------
// MFMA flash attention, swapped-QK^T softmax, prefetched staging, balanced qt.
// ---------------------------------------------------------------------------
#define KPAD 72

__global__ __launch_bounds__(256, 2) void attn_mfma_kernel(
    const __hip_bfloat16* __restrict__ Q,
    const __hip_bfloat16* __restrict__ K,
    const __hip_bfloat16* __restrict__ Vt,
    __hip_bfloat16* __restrict__ CTX)
{
    __shared__ __align__(16) __hip_bfloat16 Kl[64][KPAD];
    __shared__ __align__(16) __hip_bfloat16 Vl[64][KPAD];
    __shared__ __align__(16) __hip_bfloat16 Pl[4][32][KPAD];
    __shared__ __align__(16) float aS[4][2][16];

    const int tid = threadIdx.x;
    const int l = tid & 63;
    const int w = tid >> 6;

    const int bid = blockIdx.x + 8 * blockIdx.y + 128 * blockIdx.z;
    const int half = bid >> 8;
    const int idx = bid & 255;
    int qt = idx & 7;
    if (half) qt = 7 - qt;
    const int rest = idx >> 3;
    const int h = rest & 15;
    const int b = (rest >> 4) | (half << 1);

    const int lrow = l & 15;
    const int kg = l >> 4;
    const int kg4 = kg * 4;

    const int q0w = qt * 128 + w * 32;
    const long qrow_base = (long)b * S_DIM + q0w;

    short8 qf[2][2];
#pragma unroll
    for (int m = 0; m < 2; ++m)
#pragma unroll
        for (int ks = 0; ks < 2; ++ks)
            qf[m][ks] = *(const short8*)&Q[(qrow_base + m * 16 + lrow) * D_DIM +
                                           h * HD_DIM + ks * 32 + kg * 8];

    f32x4 ctx[2][4];
#pragma unroll
    for (int m = 0; m < 2; ++m)
#pragma unroll
        for (int d = 0; d < 4; ++d) ctx[m][d] = (f32x4){0.f, 0.f, 0.f, 0.f};
    float mrun[2] = {-1e30f, -1e30f};
    float lrun[2] = {0.f, 0.f};

    const int sr = tid >> 2;
    const int sc2 = (tid & 3) * 16;
    const __hip_bfloat16* Kg = K + ((long)b * S_DIM + sr) * D_DIM + h * HD_DIM + sc2;
    const __hip_bfloat16* Vg = Vt + ((long)((b * H_DIM + h) * HD_DIM) + sr) * S_DIM + sc2;

    const int ktmax = 2 * qt + 1;

    short8 kp0 = *(const short8*)Kg;
    short8 kp1 = *(const short8*)(Kg + 8);
    short8 vp0 = *(const short8*)Vg;
    short8 vp1 = *(const short8*)(Vg + 8);

    for (int kt = 0; kt <= ktmax; ++kt) {
        __syncthreads();
        *(short8*)&Kl[sr][sc2]     = kp0;
        *(short8*)&Kl[sr][sc2 + 8] = kp1;
        *(short8*)&Vl[sr][sc2]     = vp0;
        *(short8*)&Vl[sr][sc2 + 8] = vp1;
        if (kt < ktmax) {
            const __hip_bfloat16* kp = Kg + (long)(kt + 1) * 64 * D_DIM;
            const __hip_bfloat16* vp = Vg + (kt + 1) * 64;
            kp0 = *(const short8*)kp;
            kp1 = *(const short8*)(kp + 8);
            vp0 = *(const short8*)vp;
            vp1 = *(const short8*)(vp + 8);
        }
        __syncthreads();

        if (kt * 64 > q0w + 31) continue;

        f32x4 sac[2][4];
#pragma unroll
        for (int m = 0; m < 2; ++m)
#pragma unroll
            for (int nt = 0; nt < 4; ++nt) sac[m][nt] = (f32x4){0.f, 0.f, 0.f, 0.f};

        short8 kf[4][2];
#pragma unroll
        for (int nt = 0; nt < 4; ++nt)
#pragma unroll
            for (int ks = 0; ks < 2; ++ks)
                kf[nt][ks] = *(const short8*)&Kl[nt * 16 + lrow][ks * 32 + kg * 8];
#pragma unroll
        for (int m = 0; m < 2; ++m)
#pragma unroll
            for (int nt = 0; nt < 4; ++nt)
#pragma unroll
                for (int ks = 0; ks < 2; ++ks)
                    sac[m][nt] = __builtin_amdgcn_mfma_f32_16x16x32_bf16(
                        kf[nt][ks], qf[m][ks], sac[m][nt], 0, 0, 0);

        const bool partial = (kt * 64 + 63 > q0w);
        const int kbase = kt * 64;
#pragma unroll
        for (int m = 0; m < 2; ++m) {
            const int qg = q0w + m * 16 + lrow;
            float s[16];
#pragma unroll
            for (int nt = 0; nt < 4; ++nt)
#pragma unroll
                for (int r = 0; r < 4; ++r) {
                    float v = sac[m][nt][r];
                    if (partial && (kbase + nt * 16 + kg4 + r > qg)) v = -1e30f;
                    s[nt * 4 + r] = v;
                }
            float t8[8];
#pragma unroll
            for (int i = 0; i < 8; ++i) t8[i] = fmaxf(s[i], s[i + 8]);
#pragma unroll
            for (int i = 0; i < 4; ++i) t8[i] = fmaxf(t8[i], t8[i + 4]);
            float mx = fmaxf(fmaxf(t8[0], t8[1]), fmaxf(t8[2], t8[3]));
            mx = fmaxf(mx, __shfl_xor(mx, 16));
            mx = fmaxf(mx, __shfl_xor(mx, 32));
            const float mnew = fmaxf(mrun[m], mx);
            const float alpha = __expf(mrun[m] - mnew);
            mrun[m] = mnew;

            float p0s = 0.f, p1s = 0.f, p2s = 0.f, p3s = 0.f;
            __attribute__((aligned(8))) __hip_bfloat16 pb[16];
#pragma unroll
            for (int i = 0; i < 4; ++i) {
                float p = __expf(s[i] - mnew);      p0s += p; pb[i] = __float2bfloat16(p);
            }
#pragma unroll
            for (int i = 4; i < 8; ++i) {
                float p = __expf(s[i] - mnew);      p1s += p; pb[i] = __float2bfloat16(p);
            }
#pragma unroll
            for (int i = 8; i < 12; ++i) {
                float p = __expf(s[i] - mnew);      p2s += p; pb[i] = __float2bfloat16(p);
            }
#pragma unroll
            for (int i = 12; i < 16; ++i) {
                float p = __expf(s[i] - mnew);      p3s += p; pb[i] = __float2bfloat16(p);
            }
            float sum = (p0s + p1s) + (p2s + p3s);
            sum += __shfl_xor(sum, 16);
            sum += __shfl_xor(sum, 32);
            lrun[m] = lrun[m] * alpha + sum;

            if (kg == 0) aS[w][m][lrow] = alpha;
#pragma unroll
            for (int nt = 0; nt < 4; ++nt)
                *(uint2*)&Pl[w][m * 16 + lrow][nt * 16 + kg4] = *(uint2*)&pb[nt * 4];
        }

#pragma unroll
        for (int m = 0; m < 2; ++m) {
            f32x4 al4 = *(const f32x4*)&aS[w][m][kg4];
#pragma unroll
            for (int dt = 0; dt < 4; ++dt)
#pragma unroll
                for (int r = 0; r < 4; ++r) ctx[m][dt][r] *= al4[r];
        }

        short8 vf[4][2];
#pragma unroll
        for (int dt = 0; dt < 4; ++dt)
#pragma unroll
            for (int ks = 0; ks < 2; ++ks)
                vf[dt][ks] = *(const short8*)&Vl[dt * 16 + lrow][ks * 32 + kg * 8];
#pragma unroll
        for (int m = 0; m < 2; ++m) {
            short8 pf[2];
#pragma unroll
            for (int ks = 0; ks < 2; ++ks)
                pf[ks] = *(const short8*)&Pl[w][m * 16 + lrow][ks * 32 + kg * 8];
#pragma unroll
            for (int dt = 0; dt < 4; ++dt)
#pragma unroll
                for (int ks = 0; ks < 2; ++ks)
                    ctx[m][dt] = __builtin_amdgcn_mfma_f32_16x16x32_bf16(
                        pf[ks], vf[dt][ks], ctx[m][dt], 0, 0, 0);
        }
    }

    if (kg == 0) {
        aS[w][0][lrow] = lrun[0];
        aS[w][1][lrow] = lrun[1];
    }
#pragma unroll
    for (int m = 0; m < 2; ++m) {
        f32x4 lv = *(const f32x4*)&aS[w][m][kg4];
#pragma unroll
        for (int r = 0; r < 4; ++r) {
            const float inv_l = 1.0f / lv[r];
            const long rowoff = (qrow_base + m * 16 + kg4 + r) * D_DIM + h * HD_DIM;
#pragma unroll
            for (int dt = 0; dt < 4; ++dt)
                CTX[rowoff + dt * 16 + lrow] = __float2bfloat16(ctx[m][dt][r] * inv_l);
        }
    }
}

// ---------------------------------------------------------------------------
extern "C" void kernel_launch(void* const* d_in, const int* in_sizes, int n_in,
                              void* d_out, int out_size, void* d_ws, size_t ws_size,
                              hipStream_t stream)
{
    const float* query = (const float*)d_in[0];
    const float* key   = (const float*)d_in[1];
    const float* value = (const float*)d_in[2];
    const float* Wq = (const float*)d_in[4];
    const float* bq = (const float*)d_in[5];
    const float* Wk = (const float*)d_in[6];
    const float* bk = (const float*)d_in[7];
    const float* Wv = (const float*)d_in[8];
    const float* bv = (const float*)d_in[9];
    const float* Wo = (const float*)d_in[10];
    const float* bo = (const float*)d_in[11];

    char* wsb = (char*)d_ws;
    __hip_bfloat16* Qw    = (__hip_bfloat16*)(wsb);                 // 8 MB (pre-rope)
    __hip_bfloat16* Kw    = (__hip_bfloat16*)(wsb + (8L  << 20));   // 8 MB
    __hip_bfloat16* Vtb   = (__hip_bfloat16*)(wsb + (16L << 20));   // 8 MB
    __hip_bfloat16* Qbf   = (__hip_bfloat16*)(wsb + (24L << 20));   // 8 MB (roped)
    __hip_bfloat16* Kbf   = (__hip_bfloat16*)(wsb + (32L << 20));   // 8 MB
    __hip_bfloat16* CTXbf = (__hip_bfloat16*)(wsb + (40L << 20));   // 8 MB
    __hip_bfloat16* WtQ   = (__hip_bfloat16*)(wsb + (48L << 20));   // 2 MB
    __hip_bfloat16* WtK   = (__hip_bfloat16*)(wsb + (50L << 20));
    __hip_bfloat16* WtV   = (__hip_bfloat16*)(wsb + (52L << 20));
    __hip_bfloat16* WtO   = (__hip_bfloat16*)(wsb + (54L << 20));
    float*          tab   = (float*)(wsb + (56L << 20));            // 256 KB

    rope_table_kernel<<<128, 256, 0, stream>>>(tab);
    transpose4_to_bf16_kernel<<<dim3(32, 32, 4), 256, 0, stream>>>(
        Wq, Wk, Wv, Wo, WtQ, WtK, WtV, WtO);

    gemm_qkv_kernel<<<dim3(8, 32, 3), 256, 0, stream>>>(
        query, key, value, WtQ, WtK, WtV, bq, bk, bv, Qw, Kw, Vtb);

    rope_bf16_kernel<<<dim3(2048, 2), 256, 0, stream>>>(Qw, Kw, Qbf, Kbf, tab);

    attn_mfma_kernel<<<dim3(8, 16, 4), 256, 0, stream>>>(Qbf, Kbf, Vtb, CTXbf);

    gemm_wo_kernel<<<512, 256, 0, stream>>>(CTXbf, WtO, bo, (float*)d_out);
}